// Round 5
// baseline (971.880 us; speedup 1.0000x reference)
//
#include <hip/hip_runtime.h>
#include <math.h>

#define NN 8192
#define NE 32768
#define CC 32
#define KVN 8
#define KVT 16
#define HHD 8
#define OUTC 16
#define MIDD 64
#define RADO 3072
#define FINO 1024
#define EB 32

__device__ __forceinline__ unsigned enc_f(float f) {
  unsigned u = __float_as_uint(f);
  return (u & 0x80000000u) ? ~u : (u | 0x80000000u);
}
__device__ __forceinline__ float dec_f(unsigned u) {
  return (u & 0x80000000u) ? __uint_as_float(u & 0x7FFFFFFFu) : __uint_as_float(~u);
}

// ---------------- edge preprocessing: rn, rhat, es ----------------
__global__ void k_prep(const float* __restrict__ rel, const float* __restrict__ ef,
                       float* __restrict__ es, float* __restrict__ rhat) {
  int e = blockIdx.x * blockDim.x + threadIdx.x;
  if (e >= NE) return;
  float x = rel[e*3+0], y = rel[e*3+1], z = rel[e*3+2];
  float rn = sqrtf(x*x + y*y + z*z);
  float inv = 1.0f / (rn + 1e-12f);
  rhat[e*3+0] = x*inv; rhat[e*3+1] = y*inv; rhat[e*3+2] = z*inv;
  es[e*5+0] = rn;
  es[e*5+1] = ef[e*4+0];
  es[e*5+2] = ef[e*4+1];
  es[e*5+3] = ef[e*4+2];
  es[e*5+4] = ef[e*4+3];
}

// ---------------- radial hidden: h = relu(LN(es@W1+b1)), one wave per edge ----------------
__global__ void k_radial(const float* __restrict__ es, const float* __restrict__ W1,
                         const float* __restrict__ b1, const float* __restrict__ g,
                         const float* __restrict__ be, float* __restrict__ h) {
  int t = blockIdx.x * blockDim.x + threadIdx.x;
  int e = t >> 6, m = t & 63;
  if (e >= NE) return;
  const float* ep = es + (size_t)e*5;
  float v = b1[m];
  v = fmaf(ep[0], W1[0*64+m], v);
  v = fmaf(ep[1], W1[1*64+m], v);
  v = fmaf(ep[2], W1[2*64+m], v);
  v = fmaf(ep[3], W1[3*64+m], v);
  v = fmaf(ep[4], W1[4*64+m], v);
  float s = v;
  #pragma unroll
  for (int off = 32; off; off >>= 1) s += __shfl_xor(s, off);
  float mu = s * (1.0f/64.0f);
  float d = v - mu;
  float s2 = d*d;
  #pragma unroll
  for (int off = 32; off; off >>= 1) s2 += __shfl_xor(s2, off);
  float hv = d * rsqrtf(s2*(1.0f/64.0f) + 1e-5f) * g[m] + be[m];
  h[(size_t)e*64+m] = fmaxf(hv, 0.0f);
}

// ---------------- fused conv: R = h@W2 (on the fly) -> m0[16], m1[16][3], scaled ----------------
// m layout per edge (64 floats): [0..15]=m0, [16 + o*3 + a]=m1[o][a]
__global__ __launch_bounds__(256, 4) void k_conv(
    const float* __restrict__ h, const float* __restrict__ W2,
    const float* __restrict__ f0, const float* __restrict__ f1,
    const float* __restrict__ rhat, const float* __restrict__ scale,
    const int* __restrict__ src, float* __restrict__ m_out)
{
  __shared__ float hs[EB][65];
  __shared__ float f0s[EB][33];
  __shared__ float t1s[EB][33];
  __shared__ float f1s[EB][97];   // [c*3+a]
  __shared__ float macc[EB][80];  // 0..15: m0 ; 16..31: q01 ; 32..79: m1[o][a]
  __shared__ float rhs[EB][4];
  __shared__ float scs[EB];
  int tid = threadIdx.x;
  int e0 = blockIdx.x * EB;

  for (int idx = tid; idx < EB*64; idx += 256) {
    int e = idx >> 6, mm = idx & 63;
    hs[e][mm] = h[(size_t)(e0+e)*64 + mm];
  }
  for (int idx = tid; idx < EB; idx += 256) {
    rhs[idx][0] = rhat[(e0+idx)*3+0];
    rhs[idx][1] = rhat[(e0+idx)*3+1];
    rhs[idx][2] = rhat[(e0+idx)*3+2];
    scs[idx]    = scale[e0+idx];
  }
  for (int idx = tid; idx < EB*80; idx += 256) macc[idx/80][idx%80] = 0.0f;
  for (int idx = tid; idx < EB*CC; idx += 256) {
    int e = idx >> 5, c = idx & 31;
    int sn = src[e0+e];
    f0s[e][c] = f0[(size_t)sn*32 + c];
    float a0 = f1[(size_t)sn*96 + c*3 + 0];
    float a1 = f1[(size_t)sn*96 + c*3 + 1];
    float a2 = f1[(size_t)sn*96 + c*3 + 2];
    f1s[e][c*3+0] = a0; f1s[e][c*3+1] = a1; f1s[e][c*3+2] = a2;
    float rx = rhat[(e0+e)*3+0], ry = rhat[(e0+e)*3+1], rz = rhat[(e0+e)*3+2];
    t1s[e][c] = a0*rx + a1*ry + a2*rz;
  }
  __syncthreads();

  int eg = tid & 7;        // 8 edge groups x 4 edges
  int cs = tid >> 3;       // 32 col-slots x 8 cols
  int ebase = eg * 4;
  const float inv_s3 = 0.57735026919f;   // 1/sqrt(3)
  const float inv_s2 = 0.70710678118f;   // 1/sqrt(2)
  const float c15    = 1.22474487139f;   // sqrt(1.5)

  for (int ch = 0; ch < 12; ++ch) {
    int col0 = ch*256 + cs*8;
    float acc[4][8];
    #pragma unroll
    for (int i = 0; i < 4; ++i)
      #pragma unroll
      for (int j = 0; j < 8; ++j) acc[i][j] = 0.0f;
    const float* wp = W2 + col0;
    #pragma unroll 4
    for (int mm = 0; mm < 64; ++mm) {
      float4 wa = *reinterpret_cast<const float4*>(wp + (size_t)mm*RADO);
      float4 wb = *reinterpret_cast<const float4*>(wp + (size_t)mm*RADO + 4);
      float w[8] = {wa.x, wa.y, wa.z, wa.w, wb.x, wb.y, wb.z, wb.w};
      #pragma unroll
      for (int i = 0; i < 4; ++i) {
        float hv = hs[ebase+i][mm];
        #pragma unroll
        for (int j = 0; j < 8; ++j) acc[i][j] = fmaf(hv, w[j], acc[i][j]);
      }
    }
    int g = col0 >> 5;
    int c0 = col0 & 31;
    if (g < 16) {                       // R00: m0[o] += R*f0s
      int o = g;
      #pragma unroll
      for (int i = 0; i < 4; ++i) {
        int e = ebase+i; float p = 0.0f;
        #pragma unroll
        for (int j = 0; j < 8; ++j) p = fmaf(acc[i][j], f0s[e][c0+j], p);
        atomicAdd(&macc[e][o], p);
      }
    } else if (g < 32) {                // R01: q01[o] += R*f0s  (later x rhat)
      int o = g - 16;
      #pragma unroll
      for (int i = 0; i < 4; ++i) {
        int e = ebase+i; float p = 0.0f;
        #pragma unroll
        for (int j = 0; j < 8; ++j) p = fmaf(acc[i][j], f0s[e][c0+j], p);
        atomicAdd(&macc[e][16+o], p);
      }
    } else if (g < 48) {                // R10: m0[o] += R*(rhat.f1s)
      int o = g - 32;
      #pragma unroll
      for (int i = 0; i < 4; ++i) {
        int e = ebase+i; float p = 0.0f;
        #pragma unroll
        for (int j = 0; j < 8; ++j) p = fmaf(acc[i][j], t1s[e][c0+j], p);
        atomicAdd(&macc[e][o], p);
      }
    } else {                            // R11: m1[o][a] += R * u[j3][c][a]
      int gg = g - 48;
      int j3 = gg >> 4;
      int o  = gg & 15;
      #pragma unroll
      for (int i = 0; i < 4; ++i) {
        int e = ebase+i;
        float rx = rhs[e][0], ry = rhs[e][1], rz = rhs[e][2];
        float p0 = 0.0f, p1 = 0.0f, p2 = 0.0f;
        #pragma unroll
        for (int j = 0; j < 8; ++j) {
          int c = c0 + j;
          float fx = f1s[e][c*3+0], fy = f1s[e][c*3+1], fz = f1s[e][c*3+2];
          float u0, u1, u2;
          if (j3 == 0) {                // Q0 = I/sqrt(3)
            u0 = fx*inv_s3; u1 = fy*inv_s3; u2 = fz*inv_s3;
          } else if (j3 == 1) {         // Q1 = eps.rhat / sqrt(2)
            u0 = (rz*fy - ry*fz)*inv_s2;
            u1 = (rx*fz - rz*fx)*inv_s2;
            u2 = (ry*fx - rx*fy)*inv_s2;
          } else {                      // Q2 = sqrt(1.5)(rr^T - I/3)
            float rf = t1s[e][c];
            u0 = c15*(rx*rf - fx*(1.0f/3.0f));
            u1 = c15*(ry*rf - fy*(1.0f/3.0f));
            u2 = c15*(rz*rf - fz*(1.0f/3.0f));
          }
          float r = acc[i][j];
          p0 = fmaf(r, u0, p0); p1 = fmaf(r, u1, p1); p2 = fmaf(r, u2, p2);
        }
        atomicAdd(&macc[e][32 + o*3 + 0], p0);
        atomicAdd(&macc[e][32 + o*3 + 1], p1);
        atomicAdd(&macc[e][32 + o*3 + 2], p2);
      }
    }
  }
  __syncthreads();
  for (int idx = tid; idx < EB*64; idx += 256) {
    int e = idx >> 6, t = idx & 63;
    float sc = scs[e];
    float val;
    if (t < 16) {
      val = macc[e][t] * sc;
    } else {
      int o = (t-16)/3, a2 = (t-16)%3;
      val = (macc[e][32 + (t-16)] + macc[e][16+o]*rhs[e][a2]) * sc;
    }
    m_out[(size_t)(e0+e)*64 + t] = val;
  }
}

// ---------------- queries + zero attention accumulators ----------------
__global__ void k_query(const float* __restrict__ f0, const float* __restrict__ f1,
                        const float* __restrict__ Wq0, const float* __restrict__ Wq1,
                        float* __restrict__ q, float* __restrict__ o0, float* __restrict__ o1,
                        float* __restrict__ den, unsigned* __restrict__ mx) {
  int n = blockIdx.x * blockDim.x + threadIdx.x;
  if (n >= NN) return;
  float q0[8]  = {0,0,0,0,0,0,0,0};
  float q1x[8] = {0,0,0,0,0,0,0,0};
  float q1y[8] = {0,0,0,0,0,0,0,0};
  float q1z[8] = {0,0,0,0,0,0,0,0};
  for (int c = 0; c < 32; ++c) {
    float fv = f0[(size_t)n*32+c];
    float fx = f1[(size_t)n*96+c*3+0];
    float fy = f1[(size_t)n*96+c*3+1];
    float fz = f1[(size_t)n*96+c*3+2];
    #pragma unroll
    for (int k = 0; k < 8; ++k) {
      float w0 = Wq0[c*8+k], w1 = Wq1[c*8+k];
      q0[k]  = fmaf(fv, w0, q0[k]);
      q1x[k] = fmaf(fx, w1, q1x[k]);
      q1y[k] = fmaf(fy, w1, q1y[k]);
      q1z[k] = fmaf(fz, w1, q1z[k]);
    }
  }
  #pragma unroll
  for (int k = 0; k < 8; ++k) {
    q[(size_t)n*32+k]         = q0[k];
    q[(size_t)n*32+8+k*3+0]   = q1x[k];
    q[(size_t)n*32+8+k*3+1]   = q1y[k];
    q[(size_t)n*32+8+k*3+2]   = q1z[k];
    o0[(size_t)n*8+k] = 0.0f; den[(size_t)n*8+k] = 0.0f; mx[(size_t)n*8+k] = 0u;
  }
  #pragma unroll
  for (int i = 0; i < 24; ++i) o1[(size_t)n*24+i] = 0.0f;
}

// ---------------- attention pass 1: logits + segment max ----------------
__global__ void k_logit(const float* __restrict__ m, const float* __restrict__ q,
                        const int* __restrict__ dst, float* __restrict__ logit,
                        unsigned* __restrict__ mx) {
  int e = blockIdx.x * blockDim.x + threadIdx.x;
  if (e >= NE) return;
  int d = dst[e];
  const float* me = m + (size_t)e*64;
  const float* qd = q + (size_t)d*32;
  #pragma unroll
  for (int hh = 0; hh < 8; ++hh) {
    float l = 0.0f;
    #pragma unroll
    for (int t = 0; t < 4; ++t) {
      int col = hh*4 + t;
      float kv = (col < 8) ? me[col] : me[16 + (col-8)];
      l = fmaf(kv, qd[col], l);
    }
    l *= 0.5f;  // /sqrt(4)
    logit[(size_t)e*8+hh] = l;
    atomicMax(&mx[(size_t)d*8+hh], enc_f(l));
  }
}

// ---------------- attention pass 2: exp + segment sum ----------------
__global__ void k_attnz(float* __restrict__ logit, const unsigned* __restrict__ mx,
                        const int* __restrict__ dst, float* __restrict__ den) {
  int e = blockIdx.x * blockDim.x + threadIdx.x;
  if (e >= NE) return;
  int d = dst[e];
  #pragma unroll
  for (int hh = 0; hh < 8; ++hh) {
    float mv = dec_f(mx[(size_t)d*8+hh]);
    float z = expf(logit[(size_t)e*8+hh] - mv);
    logit[(size_t)e*8+hh] = z;
    atomicAdd(&den[(size_t)d*8+hh], z);
  }
}

// ---------------- attention pass 3: weighted scatter of values ----------------
__global__ void k_agg(const float* __restrict__ z, const float* __restrict__ den,
                      const float* __restrict__ m, const int* __restrict__ dst,
                      float* __restrict__ o0, float* __restrict__ o1) {
  int e = blockIdx.x * blockDim.x + threadIdx.x;
  if (e >= NE) return;
  int d = dst[e];
  const float* me = m + (size_t)e*64;
  #pragma unroll
  for (int hh = 0; hh < 8; ++hh) {
    float a = z[(size_t)e*8+hh] / (den[(size_t)d*8+hh] + 1e-9f);
    atomicAdd(&o0[(size_t)d*8+hh], a * me[8+hh]);
    #pragma unroll
    for (int a2 = 0; a2 < 3; ++a2)
      atomicAdd(&o1[(size_t)d*24 + hh*3 + a2], a * me[16 + (8+hh)*3 + a2]);
  }
}

// ---------------- projection + NormSE3, thread per (node, out-channel) ----------------
__global__ void k_update(const float* __restrict__ o0, const float* __restrict__ o1,
                         const float* __restrict__ f0c, const float* __restrict__ f1c,
                         const float* __restrict__ Wp0, const float* __restrict__ Wp1,
                         const float* __restrict__ ng0v, const float* __restrict__ nb0v,
                         const float* __restrict__ ng1v, const float* __restrict__ nb1v,
                         float* __restrict__ f0o, float* __restrict__ f1o) {
  int t = blockIdx.x * blockDim.x + threadIdx.x;
  int n = t >> 5, o = t & 31;
  if (n >= NN) return;
  float a0 = 0.0f, ax = 0.0f, ay = 0.0f, az = 0.0f;
  for (int c = 0; c < 8; ++c) {
    float w0 = Wp0[c*32+o], w1 = Wp1[c*32+o];
    a0 = fmaf(o0[(size_t)n*8+c], w0, a0);
    ax = fmaf(o1[(size_t)n*24+c*3+0], w1, ax);
    ay = fmaf(o1[(size_t)n*24+c*3+1], w1, ay);
    az = fmaf(o1[(size_t)n*24+c*3+2], w1, az);
  }
  for (int c = 0; c < 32; ++c) {
    float w0 = Wp0[(8+c)*32+o], w1 = Wp1[(8+c)*32+o];
    a0 = fmaf(f0c[(size_t)n*32+c], w0, a0);
    ax = fmaf(f1c[(size_t)n*96+c*3+0], w1, ax);
    ay = fmaf(f1c[(size_t)n*96+c*3+1], w1, ay);
    az = fmaf(f1c[(size_t)n*96+c*3+2], w1, az);
  }
  float nn0 = sqrtf(a0*a0 + 1e-12f);
  float nn1 = sqrtf(ax*ax + ay*ay + az*az + 1e-12f);
  float s0 = nn0, s1 = nn1;
  #pragma unroll
  for (int off = 16; off; off >>= 1) { s0 += __shfl_xor(s0, off, 32); s1 += __shfl_xor(s1, off, 32); }
  float mu0 = s0*(1.0f/32.0f), mu1 = s1*(1.0f/32.0f);
  float d0 = nn0 - mu0, d1 = nn1 - mu1;
  float v0 = d0*d0, v1 = d1*d1;
  #pragma unroll
  for (int off = 16; off; off >>= 1) { v0 += __shfl_xor(v0, off, 32); v1 += __shfl_xor(v1, off, 32); }
  float g0 = fmaxf(d0*rsqrtf(v0*(1.0f/32.0f)+1e-5f)*ng0v[o] + nb0v[o], 0.0f) / nn0;
  float g1 = fmaxf(d1*rsqrtf(v1*(1.0f/32.0f)+1e-5f)*ng1v[o] + nb1v[o], 0.0f) / nn1;
  f0o[(size_t)n*32+o] = a0*g0;
  f1o[(size_t)n*96+o*3+0] = ax*g1;
  f1o[(size_t)n*96+o*3+1] = ay*g1;
  f1o[(size_t)n*96+o*3+2] = az*g1;
}

// ---------------- final fused conv -> scatter to output ----------------
__global__ __launch_bounds__(256, 4) void k_fconv(
    const float* __restrict__ h, const float* __restrict__ W2,
    const float* __restrict__ f0, const float* __restrict__ f1,
    const float* __restrict__ rhat, const float* __restrict__ scale,
    const int* __restrict__ src, const int* __restrict__ dst, float* __restrict__ out)
{
  __shared__ float hs[EB][65];
  __shared__ float f0s[EB][33];
  __shared__ float t1s[EB][33];
  __shared__ float macc[EB][16];
  __shared__ float scs[EB];
  int tid = threadIdx.x;
  int e0 = blockIdx.x * EB;

  for (int idx = tid; idx < EB*64; idx += 256) {
    int e = idx >> 6, mm = idx & 63;
    hs[e][mm] = h[(size_t)(e0+e)*64 + mm];
  }
  for (int idx = tid; idx < EB; idx += 256) scs[idx] = scale[e0+idx];
  for (int idx = tid; idx < EB*16; idx += 256) macc[idx>>4][idx&15] = 0.0f;
  for (int idx = tid; idx < EB*CC; idx += 256) {
    int e = idx >> 5, c = idx & 31;
    int sn = src[e0+e];
    f0s[e][c] = f0[(size_t)sn*32 + c];
    float a0 = f1[(size_t)sn*96 + c*3 + 0];
    float a1 = f1[(size_t)sn*96 + c*3 + 1];
    float a2 = f1[(size_t)sn*96 + c*3 + 2];
    float rx = rhat[(e0+e)*3+0], ry = rhat[(e0+e)*3+1], rz = rhat[(e0+e)*3+2];
    t1s[e][c] = a0*rx + a1*ry + a2*rz;
  }
  __syncthreads();

  int eg = tid & 7;
  int cs = tid >> 3;
  int ebase = eg * 4;
  for (int ch = 0; ch < 4; ++ch) {
    int col0 = ch*256 + cs*8;
    float acc[4][8];
    #pragma unroll
    for (int i = 0; i < 4; ++i)
      #pragma unroll
      for (int j = 0; j < 8; ++j) acc[i][j] = 0.0f;
    const float* wp = W2 + col0;
    #pragma unroll 4
    for (int mm = 0; mm < 64; ++mm) {
      float4 wa = *reinterpret_cast<const float4*>(wp + (size_t)mm*FINO);
      float4 wb = *reinterpret_cast<const float4*>(wp + (size_t)mm*FINO + 4);
      float w[8] = {wa.x, wa.y, wa.z, wa.w, wb.x, wb.y, wb.z, wb.w};
      #pragma unroll
      for (int i = 0; i < 4; ++i) {
        float hv = hs[ebase+i][mm];
        #pragma unroll
        for (int j = 0; j < 8; ++j) acc[i][j] = fmaf(hv, w[j], acc[i][j]);
      }
    }
    int g = col0 >> 5, c0 = col0 & 31;
    bool t00 = (g < 16);
    int o = t00 ? g : (g - 16);
    #pragma unroll
    for (int i = 0; i < 4; ++i) {
      int e = ebase+i; float p = 0.0f;
      #pragma unroll
      for (int j = 0; j < 8; ++j)
        p = fmaf(acc[i][j], t00 ? f0s[e][c0+j] : t1s[e][c0+j], p);
      atomicAdd(&macc[e][o], p);
    }
  }
  __syncthreads();
  for (int idx = tid; idx < EB*16; idx += 256) {
    int e = idx >> 4, o = idx & 15;
    float v = macc[e][o] * scs[e];
    atomicAdd(&out[(size_t)dst[e0+e]*16 + o], v);
  }
}

extern "C" void kernel_launch(void* const* d_in, const int* in_sizes, int n_in,
                              void* d_out, int out_size, void* d_ws, size_t ws_size,
                              hipStream_t stream) {
  (void)in_sizes; (void)n_in; (void)ws_size;
  const float* nf0  = (const float*)d_in[0];
  const float* nf1  = (const float*)d_in[1];
  const float* ef0  = (const float*)d_in[2];
  const float* rel  = (const float*)d_in[3];
  const float* scale= (const float*)d_in[4];
  const int*   src  = (const int*)d_in[5];
  const int*   dst  = (const int*)d_in[6];
  const float* rW1  = (const float*)d_in[7];
  const float* rb1  = (const float*)d_in[8];
  const float* rg   = (const float*)d_in[9];
  const float* rbe  = (const float*)d_in[10];
  const float* rW2  = (const float*)d_in[11];
  const float* Wq0  = (const float*)d_in[12];
  const float* Wq1  = (const float*)d_in[13];
  const float* Wp0  = (const float*)d_in[14];
  const float* Wp1  = (const float*)d_in[15];
  const float* ng0  = (const float*)d_in[16];
  const float* nb0  = (const float*)d_in[17];
  const float* ng1  = (const float*)d_in[18];
  const float* nb1  = (const float*)d_in[19];
  const float* fW1  = (const float*)d_in[20];
  const float* fb1  = (const float*)d_in[21];
  const float* fg   = (const float*)d_in[22];
  const float* fbe  = (const float*)d_in[23];
  const float* fW2  = (const float*)d_in[24];

  float* ws = (float*)d_ws;
  size_t off = 0;
  float* es    = ws + off; off += (size_t)NE*5;
  float* rhat  = ws + off; off += (size_t)NE*3;
  float* h     = ws + off; off += (size_t)NE*64;
  float* m     = ws + off; off += (size_t)NE*64;
  float* q     = ws + off; off += (size_t)NN*32;
  float* logit = ws + off; off += (size_t)NE*8;
  unsigned* mx = (unsigned*)(ws + off); off += (size_t)NN*8;
  float* den   = ws + off; off += (size_t)NN*8;
  float* o0    = ws + off; off += (size_t)NN*8;
  float* o1    = ws + off; off += (size_t)NN*24;
  float* f0a   = ws + off; off += (size_t)NN*32;
  float* f1a   = ws + off; off += (size_t)NN*96;
  float* f0b   = ws + off; off += (size_t)NN*32;
  float* f1b   = ws + off; off += (size_t)NN*96;

  k_prep<<<NE/256, 256, 0, stream>>>(rel, ef0, es, rhat);

  const float* f0c = nf0; const float* f1c = nf1;
  float* f0n = f0a; float* f1n = f1a;
  for (int l = 0; l < 2; ++l) {
    k_radial<<<NE*64/256, 256, 0, stream>>>(es, rW1 + l*320, rb1 + l*64, rg + l*64, rbe + l*64, h);
    k_conv<<<NE/EB, 256, 0, stream>>>(h, rW2 + (size_t)l*64*RADO, f0c, f1c, rhat, scale, src, m);
    k_query<<<NN/256, 256, 0, stream>>>(f0c, f1c, Wq0 + l*256, Wq1 + l*256, q, o0, o1, den, mx);
    k_logit<<<NE/256, 256, 0, stream>>>(m, q, dst, logit, mx);
    k_attnz<<<NE/256, 256, 0, stream>>>(logit, mx, dst, den);
    k_agg<<<NE/256, 256, 0, stream>>>(logit, den, m, dst, o0, o1);
    k_update<<<NN*32/256, 256, 0, stream>>>(o0, o1, f0c, f1c, Wp0 + l*1280, Wp1 + l*1280,
                                            ng0 + l*32, nb0 + l*32, ng1 + l*32, nb1 + l*32,
                                            f0n, f1n);
    f0c = f0n; f1c = f1n; f0n = f0b; f1n = f1b;
  }
  k_radial<<<NE*64/256, 256, 0, stream>>>(es, fW1, fb1, fg, fbe, h);
  hipMemsetAsync(d_out, 0, (size_t)out_size*sizeof(float), stream);
  k_fconv<<<NE/EB, 256, 0, stream>>>(h, fW2, f0c, f1c, rhat, scale, src, dst, (float*)d_out);
}

// Round 7
// 822.062 us; speedup vs baseline: 1.1822x; 1.1822x over previous
//
#include <hip/hip_runtime.h>
#include <math.h>

#define NN 8192
#define NE 32768
#define CC 32
#define EB 32

typedef __attribute__((ext_vector_type(8))) short s16x8;
typedef __attribute__((ext_vector_type(4))) float f32x4;

__device__ __forceinline__ unsigned enc_f(float f) {
  unsigned u = __float_as_uint(f);
  return (u & 0x80000000u) ? ~u : (u | 0x80000000u);
}
__device__ __forceinline__ float dec_f(unsigned u) {
  return (u & 0x80000000u) ? __uint_as_float(u & 0x7FFFFFFFu) : __uint_as_float(~u);
}
__device__ __forceinline__ unsigned short f2bf(float f) {
  unsigned u = __float_as_uint(f);
  u += 0x7FFFu + ((u >> 16) & 1u);
  return (unsigned short)(u >> 16);
}

// ---------------- edge preprocessing ----------------
__global__ void k_prep(const float* __restrict__ rel, const float* __restrict__ ef,
                       float* __restrict__ es, float* __restrict__ rhat) {
  int e = blockIdx.x * blockDim.x + threadIdx.x;
  if (e >= NE) return;
  float x = rel[e*3+0], y = rel[e*3+1], z = rel[e*3+2];
  float rn = sqrtf(x*x + y*y + z*z);
  float inv = 1.0f / (rn + 1e-12f);
  rhat[e*3+0] = x*inv; rhat[e*3+1] = y*inv; rhat[e*3+2] = z*inv;
  es[e*5+0] = rn;
  es[e*5+1] = ef[e*4+0];
  es[e*5+2] = ef[e*4+1];
  es[e*5+3] = ef[e*4+2];
  es[e*5+4] = ef[e*4+3];
}

// ---------------- radial hidden -> bf16 ----------------
__global__ void k_radial(const float* __restrict__ es, const float* __restrict__ W1,
                         const float* __restrict__ b1, const float* __restrict__ g,
                         const float* __restrict__ be, unsigned short* __restrict__ h) {
  int t = blockIdx.x * blockDim.x + threadIdx.x;
  int e = t >> 6, m = t & 63;
  if (e >= NE) return;
  const float* ep = es + (size_t)e*5;
  float v = b1[m];
  v = fmaf(ep[0], W1[0*64+m], v);
  v = fmaf(ep[1], W1[1*64+m], v);
  v = fmaf(ep[2], W1[2*64+m], v);
  v = fmaf(ep[3], W1[3*64+m], v);
  v = fmaf(ep[4], W1[4*64+m], v);
  float s = v;
  #pragma unroll
  for (int off = 32; off; off >>= 1) s += __shfl_xor(s, off);
  float mu = s * (1.0f/64.0f);
  float d = v - mu;
  float s2 = d*d;
  #pragma unroll
  for (int off = 32; off; off >>= 1) s2 += __shfl_xor(s2, off);
  float hv = d * rsqrtf(s2*(1.0f/64.0f) + 1e-5f) * g[m] + be[m];
  h[(size_t)e*64+m] = f2bf(fmaxf(hv, 0.0f));
}

// ---------------- W2 -> bf16 swizzled into B-fragment order ----------------
// dst[((t*2+s)*64 + lane)*8 + j] = bf16( W2[ s*32 + (lane>>4)*8 + j ][ t*16 + (lane&15) ] )
__global__ void k_w2cvt(const float* __restrict__ W2, unsigned short* __restrict__ dstp, int N) {
  int idx = blockIdx.x * blockDim.x + threadIdx.x;
  int total = (N >> 4) * 128;  // (N/16)*2*64
  if (idx >= total) return;
  int l = idx & 63;
  int s = (idx >> 6) & 1;
  int t = idx >> 7;
  int kb = s*32 + (l >> 4)*8;
  int col = t*16 + (l & 15);
  s16x8 v;
  #pragma unroll
  for (int j = 0; j < 8; ++j) v[j] = (short)f2bf(W2[(size_t)(kb + j)*N + col]);
  *reinterpret_cast<s16x8*>(dstp + (size_t)idx*8) = v;
}

// ---------------- fused conv via MFMA: R = h@W2 chunked through LDS ----------------
// m layout per edge (64 floats): [0..15]=m0, [16 + o*3 + a]=m1[o][a]
__global__ __launch_bounds__(256) void k_conv_mfma(
    const unsigned short* __restrict__ hbf, const unsigned short* __restrict__ w2s,
    const float* __restrict__ f0, const float* __restrict__ f1,
    const float* __restrict__ rhat, const float* __restrict__ scale,
    const int* __restrict__ src, float* __restrict__ m_out)
{
  __shared__ float f0s[EB][33];
  __shared__ float t1s[EB][33];
  __shared__ float f1s[EB][97];
  __shared__ float rhs[EB][4];
  __shared__ float scs[EB];
  __shared__ float macc[EB][80];   // 0..15 m0 ; 16..31 q01 ; 32..79 m1
  __shared__ float Rl[EB*68];      // 32x64 R-chunk, stride 68 (16B-aligned rows, <=2-way bank)
  int tid = threadIdx.x;
  int e0 = blockIdx.x * EB;

  for (int idx = tid; idx < EB; idx += 256) {
    rhs[idx][0] = rhat[(e0+idx)*3+0];
    rhs[idx][1] = rhat[(e0+idx)*3+1];
    rhs[idx][2] = rhat[(e0+idx)*3+2];
    scs[idx]    = scale[e0+idx];
  }
  for (int idx = tid; idx < EB*80; idx += 256) macc[idx/80][idx%80] = 0.0f;
  for (int idx = tid; idx < EB*CC; idx += 256) {
    int e = idx >> 5, c = idx & 31;
    int sn = src[e0+e];
    f0s[e][c] = f0[(size_t)sn*32 + c];
    float a0 = f1[(size_t)sn*96 + c*3 + 0];
    float a1 = f1[(size_t)sn*96 + c*3 + 1];
    float a2 = f1[(size_t)sn*96 + c*3 + 2];
    f1s[e][c*3+0] = a0; f1s[e][c*3+1] = a1; f1s[e][c*3+2] = a2;
    float rx = rhat[(e0+e)*3+0], ry = rhat[(e0+e)*3+1], rz = rhat[(e0+e)*3+2];
    t1s[e][c] = a0*rx + a1*ry + a2*rz;
  }

  int lane = tid & 63, wv = tid >> 6;
  // A fragments: lane holds h[row][k0..k0+7], row=lane&15 (+16), k0=(lane>>4)*8 (+32)
  s16x8 af00, af01, af10, af11;
  {
    const unsigned short* hb = hbf + (size_t)e0*64;
    int row = lane & 15;
    int ko  = (lane >> 4) * 8;
    af00 = *reinterpret_cast<const s16x8*>(hb + (size_t)row*64 + ko);
    af01 = *reinterpret_cast<const s16x8*>(hb + (size_t)row*64 + 32 + ko);
    af10 = *reinterpret_cast<const s16x8*>(hb + (size_t)(row+16)*64 + ko);
    af11 = *reinterpret_cast<const s16x8*>(hb + (size_t)(row+16)*64 + 32 + ko);
  }
  __syncthreads();

  const float inv_s3 = 0.57735026919f;
  const float inv_s2 = 0.70710678118f;
  const float c15    = 1.22474487139f;

  for (int ch = 0; ch < 48; ++ch) {           // 48 chunks x 64 cols = 3072
    int t = ch*4 + wv;                        // col-tile (16 cols) per wave
    const s16x8* bp = reinterpret_cast<const s16x8*>(w2s + ((size_t)(t*2)*64 + lane)*8);
    s16x8 b0 = bp[0];
    s16x8 b1 = bp[64];
    f32x4 a0v = {0.f,0.f,0.f,0.f}, a1v = {0.f,0.f,0.f,0.f};
    a0v = __builtin_amdgcn_mfma_f32_16x16x32_bf16(af00, b0, a0v, 0, 0, 0);
    a0v = __builtin_amdgcn_mfma_f32_16x16x32_bf16(af01, b1, a0v, 0, 0, 0);
    a1v = __builtin_amdgcn_mfma_f32_16x16x32_bf16(af10, b0, a1v, 0, 0, 0);
    a1v = __builtin_amdgcn_mfma_f32_16x16x32_bf16(af11, b1, a1v, 0, 0, 0);
    // D layout: col=lane&15, row=(lane>>4)*4+reg
    int cl = wv*16 + (lane & 15);
    int rb = (lane >> 4) * 4;
    #pragma unroll
    for (int r = 0; r < 4; ++r) {
      Rl[(rb+r)*68 + cl]    = a0v[r];
      Rl[(rb+16+r)*68 + cl] = a1v[r];
    }
    __syncthreads();
    // epilogue on this 64-col chunk: thread = (edge e, 8-col slot cs)
    {
      int e  = tid >> 3;
      int cs = tid & 7;
      int g  = ch*2 + (cs >> 2);          // global 32-col group
      int c0 = (cs & 3) * 8;              // channel offset in group
      const float* rp = &Rl[e*68 + (cs >> 2)*32 + c0];
      float4 ra  = *reinterpret_cast<const float4*>(rp);
      float4 rbv = *reinterpret_cast<const float4*>(rp + 4);
      float r8[8] = {ra.x, ra.y, ra.z, ra.w, rbv.x, rbv.y, rbv.z, rbv.w};
      if (g < 32) {                        // R00 (g<16) and R01 (16..31) both use f0s
        float p = 0.0f;
        #pragma unroll
        for (int j = 0; j < 8; ++j) p = fmaf(r8[j], f0s[e][c0+j], p);
        atomicAdd(&macc[e][g], p);
      } else if (g < 48) {                 // R10: with rhat.f1
        float p = 0.0f;
        #pragma unroll
        for (int j = 0; j < 8; ++j) p = fmaf(r8[j], t1s[e][c0+j], p);
        atomicAdd(&macc[e][g-32], p);
      } else {                             // R11
        int gg = g - 48;
        int j3 = gg >> 4;
        int o  = gg & 15;
        float rx = rhs[e][0], ry = rhs[e][1], rz = rhs[e][2];
        float p0 = 0.0f, p1 = 0.0f, p2 = 0.0f;
        #pragma unroll
        for (int j = 0; j < 8; ++j) {
          int c = c0 + j;
          float fx = f1s[e][c*3+0], fy = f1s[e][c*3+1], fz = f1s[e][c*3+2];
          float u0, u1, u2;
          if (j3 == 0) {
            u0 = fx*inv_s3; u1 = fy*inv_s3; u2 = fz*inv_s3;
          } else if (j3 == 1) {
            u0 = (rz*fy - ry*fz)*inv_s2;
            u1 = (rx*fz - rz*fx)*inv_s2;
            u2 = (ry*fx - rx*fy)*inv_s2;
          } else {
            float rf = t1s[e][c];
            u0 = c15*(rx*rf - fx*(1.0f/3.0f));
            u1 = c15*(ry*rf - fy*(1.0f/3.0f));
            u2 = c15*(rz*rf - fz*(1.0f/3.0f));
          }
          float r = r8[j];
          p0 = fmaf(r, u0, p0); p1 = fmaf(r, u1, p1); p2 = fmaf(r, u2, p2);
        }
        atomicAdd(&macc[e][32 + o*3 + 0], p0);
        atomicAdd(&macc[e][32 + o*3 + 1], p1);
        atomicAdd(&macc[e][32 + o*3 + 2], p2);
      }
    }
    __syncthreads();
  }
  for (int idx = tid; idx < EB*64; idx += 256) {
    int e = idx >> 6, t2 = idx & 63;
    float sc = scs[e];
    float val;
    if (t2 < 16) {
      val = macc[e][t2] * sc;
    } else {
      int o = (t2-16)/3, a2 = (t2-16)%3;
      val = (macc[e][32 + (t2-16)] + macc[e][16+o]*rhs[e][a2]) * sc;
    }
    m_out[(size_t)(e0+e)*64 + t2] = val;
  }
}

// ---------------- queries + zero attention accumulators ----------------
__global__ void k_query(const float* __restrict__ f0, const float* __restrict__ f1,
                        const float* __restrict__ Wq0, const float* __restrict__ Wq1,
                        float* __restrict__ q, float* __restrict__ o0, float* __restrict__ o1,
                        float* __restrict__ den, unsigned* __restrict__ mx) {
  int n = blockIdx.x * blockDim.x + threadIdx.x;
  if (n >= NN) return;
  float q0[8]  = {0,0,0,0,0,0,0,0};
  float q1x[8] = {0,0,0,0,0,0,0,0};
  float q1y[8] = {0,0,0,0,0,0,0,0};
  float q1z[8] = {0,0,0,0,0,0,0,0};
  for (int c = 0; c < 32; ++c) {
    float fv = f0[(size_t)n*32+c];
    float fx = f1[(size_t)n*96+c*3+0];
    float fy = f1[(size_t)n*96+c*3+1];
    float fz = f1[(size_t)n*96+c*3+2];
    #pragma unroll
    for (int k = 0; k < 8; ++k) {
      float w0 = Wq0[c*8+k], w1 = Wq1[c*8+k];
      q0[k]  = fmaf(fv, w0, q0[k]);
      q1x[k] = fmaf(fx, w1, q1x[k]);
      q1y[k] = fmaf(fy, w1, q1y[k]);
      q1z[k] = fmaf(fz, w1, q1z[k]);
    }
  }
  #pragma unroll
  for (int k = 0; k < 8; ++k) {
    q[(size_t)n*32+k]         = q0[k];
    q[(size_t)n*32+8+k*3+0]   = q1x[k];
    q[(size_t)n*32+8+k*3+1]   = q1y[k];
    q[(size_t)n*32+8+k*3+2]   = q1z[k];
    o0[(size_t)n*8+k] = 0.0f; den[(size_t)n*8+k] = 0.0f; mx[(size_t)n*8+k] = 0u;
  }
  #pragma unroll
  for (int i = 0; i < 24; ++i) o1[(size_t)n*24+i] = 0.0f;
}

// ---------------- attention pass 1 ----------------
__global__ void k_logit(const float* __restrict__ m, const float* __restrict__ q,
                        const int* __restrict__ dst, float* __restrict__ logit,
                        unsigned* __restrict__ mx) {
  int e = blockIdx.x * blockDim.x + threadIdx.x;
  if (e >= NE) return;
  int d = dst[e];
  const float* me = m + (size_t)e*64;
  const float* qd = q + (size_t)d*32;
  #pragma unroll
  for (int hh = 0; hh < 8; ++hh) {
    float l = 0.0f;
    #pragma unroll
    for (int t = 0; t < 4; ++t) {
      int col = hh*4 + t;
      float kv = (col < 8) ? me[col] : me[16 + (col-8)];
      l = fmaf(kv, qd[col], l);
    }
    l *= 0.5f;
    logit[(size_t)e*8+hh] = l;
    atomicMax(&mx[(size_t)d*8+hh], enc_f(l));
  }
}

// ---------------- attention pass 2 ----------------
__global__ void k_attnz(float* __restrict__ logit, const unsigned* __restrict__ mx,
                        const int* __restrict__ dst, float* __restrict__ den) {
  int e = blockIdx.x * blockDim.x + threadIdx.x;
  if (e >= NE) return;
  int d = dst[e];
  #pragma unroll
  for (int hh = 0; hh < 8; ++hh) {
    float mv = dec_f(mx[(size_t)d*8+hh]);
    float z = expf(logit[(size_t)e*8+hh] - mv);
    logit[(size_t)e*8+hh] = z;
    atomicAdd(&den[(size_t)d*8+hh], z);
  }
}

// ---------------- attention pass 3 ----------------
__global__ void k_agg(const float* __restrict__ z, const float* __restrict__ den,
                      const float* __restrict__ m, const int* __restrict__ dst,
                      float* __restrict__ o0, float* __restrict__ o1) {
  int e = blockIdx.x * blockDim.x + threadIdx.x;
  if (e >= NE) return;
  int d = dst[e];
  const float* me = m + (size_t)e*64;
  #pragma unroll
  for (int hh = 0; hh < 8; ++hh) {
    float a = z[(size_t)e*8+hh] / (den[(size_t)d*8+hh] + 1e-9f);
    atomicAdd(&o0[(size_t)d*8+hh], a * me[8+hh]);
    #pragma unroll
    for (int a2 = 0; a2 < 3; ++a2)
      atomicAdd(&o1[(size_t)d*24 + hh*3 + a2], a * me[16 + (8+hh)*3 + a2]);
  }
}

// ---------------- projection + NormSE3 ----------------
__global__ void k_update(const float* __restrict__ o0, const float* __restrict__ o1,
                         const float* __restrict__ f0c, const float* __restrict__ f1c,
                         const float* __restrict__ Wp0, const float* __restrict__ Wp1,
                         const float* __restrict__ ng0v, const float* __restrict__ nb0v,
                         const float* __restrict__ ng1v, const float* __restrict__ nb1v,
                         float* __restrict__ f0o, float* __restrict__ f1o) {
  int t = blockIdx.x * blockDim.x + threadIdx.x;
  int n = t >> 5, o = t & 31;
  if (n >= NN) return;
  float a0 = 0.0f, ax = 0.0f, ay = 0.0f, az = 0.0f;
  for (int c = 0; c < 8; ++c) {
    float w0 = Wp0[c*32+o], w1 = Wp1[c*32+o];
    a0 = fmaf(o0[(size_t)n*8+c], w0, a0);
    ax = fmaf(o1[(size_t)n*24+c*3+0], w1, ax);
    ay = fmaf(o1[(size_t)n*24+c*3+1], w1, ay);
    az = fmaf(o1[(size_t)n*24+c*3+2], w1, az);
  }
  for (int c = 0; c < 32; ++c) {
    float w0 = Wp0[(8+c)*32+o], w1 = Wp1[(8+c)*32+o];
    a0 = fmaf(f0c[(size_t)n*32+c], w0, a0);
    ax = fmaf(f1c[(size_t)n*96+c*3+0], w1, ax);
    ay = fmaf(f1c[(size_t)n*96+c*3+1], w1, ay);
    az = fmaf(f1c[(size_t)n*96+c*3+2], w1, az);
  }
  float nn0 = sqrtf(a0*a0 + 1e-12f);
  float nn1 = sqrtf(ax*ax + ay*ay + az*az + 1e-12f);
  float s0 = nn0, s1 = nn1;
  #pragma unroll
  for (int off = 16; off; off >>= 1) { s0 += __shfl_xor(s0, off, 32); s1 += __shfl_xor(s1, off, 32); }
  float mu0 = s0*(1.0f/32.0f), mu1 = s1*(1.0f/32.0f);
  float d0 = nn0 - mu0, d1 = nn1 - mu1;
  float v0 = d0*d0, v1 = d1*d1;
  #pragma unroll
  for (int off = 16; off; off >>= 1) { v0 += __shfl_xor(v0, off, 32); v1 += __shfl_xor(v1, off, 32); }
  float g0 = fmaxf(d0*rsqrtf(v0*(1.0f/32.0f)+1e-5f)*ng0v[o] + nb0v[o], 0.0f) / nn0;
  float g1 = fmaxf(d1*rsqrtf(v1*(1.0f/32.0f)+1e-5f)*ng1v[o] + nb1v[o], 0.0f) / nn1;
  f0o[(size_t)n*32+o] = a0*g0;
  f1o[(size_t)n*96+o*3+0] = ax*g1;
  f1o[(size_t)n*96+o*3+1] = ay*g1;
  f1o[(size_t)n*96+o*3+2] = az*g1;
}

// ---------------- final conv via MFMA -> scatter ----------------
__global__ __launch_bounds__(256) void k_fconv_mfma(
    const unsigned short* __restrict__ hbf, const unsigned short* __restrict__ w2s,
    const float* __restrict__ f0, const float* __restrict__ f1,
    const float* __restrict__ rhat, const float* __restrict__ scale,
    const int* __restrict__ src, const int* __restrict__ dst, float* __restrict__ out)
{
  __shared__ float f0s[EB][33];
  __shared__ float t1s[EB][33];
  __shared__ float macc[EB][16];
  __shared__ float scs[EB];
  __shared__ float Rl[EB*68];
  int tid = threadIdx.x;
  int e0 = blockIdx.x * EB;

  for (int idx = tid; idx < EB; idx += 256) scs[idx] = scale[e0+idx];
  for (int idx = tid; idx < EB*16; idx += 256) macc[idx>>4][idx&15] = 0.0f;
  for (int idx = tid; idx < EB*CC; idx += 256) {
    int e = idx >> 5, c = idx & 31;
    int sn = src[e0+e];
    f0s[e][c] = f0[(size_t)sn*32 + c];
    float a0 = f1[(size_t)sn*96 + c*3 + 0];
    float a1 = f1[(size_t)sn*96 + c*3 + 1];
    float a2 = f1[(size_t)sn*96 + c*3 + 2];
    float rx = rhat[(e0+e)*3+0], ry = rhat[(e0+e)*3+1], rz = rhat[(e0+e)*3+2];
    t1s[e][c] = a0*rx + a1*ry + a2*rz;
  }
  int lane = tid & 63, wv = tid >> 6;
  s16x8 af00, af01, af10, af11;
  {
    const unsigned short* hb = hbf + (size_t)e0*64;
    int row = lane & 15;
    int ko  = (lane >> 4) * 8;
    af00 = *reinterpret_cast<const s16x8*>(hb + (size_t)row*64 + ko);
    af01 = *reinterpret_cast<const s16x8*>(hb + (size_t)row*64 + 32 + ko);
    af10 = *reinterpret_cast<const s16x8*>(hb + (size_t)(row+16)*64 + ko);
    af11 = *reinterpret_cast<const s16x8*>(hb + (size_t)(row+16)*64 + 32 + ko);
  }
  __syncthreads();

  for (int ch = 0; ch < 16; ++ch) {          // 16 chunks x 64 cols = 1024
    int t = ch*4 + wv;
    const s16x8* bp = reinterpret_cast<const s16x8*>(w2s + ((size_t)(t*2)*64 + lane)*8);
    s16x8 b0 = bp[0];
    s16x8 b1 = bp[64];
    f32x4 a0v = {0.f,0.f,0.f,0.f}, a1v = {0.f,0.f,0.f,0.f};
    a0v = __builtin_amdgcn_mfma_f32_16x16x32_bf16(af00, b0, a0v, 0, 0, 0);
    a0v = __builtin_amdgcn_mfma_f32_16x16x32_bf16(af01, b1, a0v, 0, 0, 0);
    a1v = __builtin_amdgcn_mfma_f32_16x16x32_bf16(af10, b0, a1v, 0, 0, 0);
    a1v = __builtin_amdgcn_mfma_f32_16x16x32_bf16(af11, b1, a1v, 0, 0, 0);
    int cl = wv*16 + (lane & 15);
    int rb = (lane >> 4) * 4;
    #pragma unroll
    for (int r = 0; r < 4; ++r) {
      Rl[(rb+r)*68 + cl]    = a0v[r];
      Rl[(rb+16+r)*68 + cl] = a1v[r];
    }
    __syncthreads();
    {
      int e  = tid >> 3;
      int cs = tid & 7;
      int g  = ch*2 + (cs >> 2);
      int c0 = (cs & 3) * 8;
      const float* rp = &Rl[e*68 + (cs >> 2)*32 + c0];
      float4 ra  = *reinterpret_cast<const float4*>(rp);
      float4 rbv = *reinterpret_cast<const float4*>(rp + 4);
      float r8[8] = {ra.x, ra.y, ra.z, ra.w, rbv.x, rbv.y, rbv.z, rbv.w};
      const float* F = (g < 16) ? &f0s[e][0] : &t1s[e][0];
      int o = (g < 16) ? g : g - 16;
      float p = 0.0f;
      #pragma unroll
      for (int j = 0; j < 8; ++j) p = fmaf(r8[j], F[c0+j], p);
      atomicAdd(&macc[e][o], p);
    }
    __syncthreads();
  }
  for (int idx = tid; idx < EB*16; idx += 256) {
    int e = idx >> 4, o = idx & 15;
    atomicAdd(&out[(size_t)dst[e0+e]*16 + o], macc[e][o]*scs[e]);
  }
}

extern "C" void kernel_launch(void* const* d_in, const int* in_sizes, int n_in,
                              void* d_out, int out_size, void* d_ws, size_t ws_size,
                              hipStream_t stream) {
  (void)in_sizes; (void)n_in; (void)ws_size;
  const float* nf0  = (const float*)d_in[0];
  const float* nf1  = (const float*)d_in[1];
  const float* ef0  = (const float*)d_in[2];
  const float* rel  = (const float*)d_in[3];
  const float* scale= (const float*)d_in[4];
  const int*   src  = (const int*)d_in[5];
  const int*   dst  = (const int*)d_in[6];
  const float* rW1  = (const float*)d_in[7];
  const float* rb1  = (const float*)d_in[8];
  const float* rg   = (const float*)d_in[9];
  const float* rbe  = (const float*)d_in[10];
  const float* rW2  = (const float*)d_in[11];
  const float* Wq0  = (const float*)d_in[12];
  const float* Wq1  = (const float*)d_in[13];
  const float* Wp0  = (const float*)d_in[14];
  const float* Wp1  = (const float*)d_in[15];
  const float* ng0  = (const float*)d_in[16];
  const float* nb0  = (const float*)d_in[17];
  const float* ng1  = (const float*)d_in[18];
  const float* nb1  = (const float*)d_in[19];
  const float* fW1  = (const float*)d_in[20];
  const float* fb1  = (const float*)d_in[21];
  const float* fg   = (const float*)d_in[22];
  const float* fbe  = (const float*)d_in[23];
  const float* fW2  = (const float*)d_in[24];

  float* ws = (float*)d_ws;
  size_t off = 0;
  float* es    = ws + off; off += (size_t)NE*5;
  float* rhat  = ws + off; off += (size_t)NE*3;
  float* m     = ws + off; off += (size_t)NE*64;
  float* q     = ws + off; off += (size_t)NN*32;
  float* logit = ws + off; off += (size_t)NE*8;
  unsigned* mx = (unsigned*)(ws + off); off += (size_t)NN*8;
  float* den   = ws + off; off += (size_t)NN*8;
  float* o0    = ws + off; off += (size_t)NN*8;
  float* o1    = ws + off; off += (size_t)NN*24;
  float* f0a   = ws + off; off += (size_t)NN*32;
  float* f1a   = ws + off; off += (size_t)NN*96;
  float* f0b   = ws + off; off += (size_t)NN*32;
  float* f1b   = ws + off; off += (size_t)NN*96;
  unsigned short* usbase = (unsigned short*)(ws + off);
  unsigned short* hbf  = usbase;                               // NE*64
  unsigned short* w2s0 = hbf  + (size_t)NE*64;                 // 192*2*64*8 = 196608
  unsigned short* w2s1 = w2s0 + 196608;
  unsigned short* w2sf = w2s1 + 196608;                        // 64*2*64*8 = 65536

  // weight pre-swizzle (bf16 B-fragment order), once per launch
  k_w2cvt<<<96, 256, 0, stream>>>(rW2,            w2s0, 3072);
  k_w2cvt<<<96, 256, 0, stream>>>(rW2 + 64*3072,  w2s1, 3072);
  k_w2cvt<<<32, 256, 0, stream>>>(fW2,            w2sf, 1024);

  k_prep<<<NE/256, 256, 0, stream>>>(rel, ef0, es, rhat);

  const float* f0c = nf0; const float* f1c = nf1;
  float* f0n = f0a; float* f1n = f1a;
  for (int l = 0; l < 2; ++l) {
    k_radial<<<NE*64/256, 256, 0, stream>>>(es, rW1 + l*320, rb1 + l*64, rg + l*64, rbe + l*64, hbf);
    k_conv_mfma<<<NE/EB, 256, 0, stream>>>(hbf, (l == 0) ? w2s0 : w2s1, f0c, f1c, rhat, scale, src, m);
    k_query<<<NN/256, 256, 0, stream>>>(f0c, f1c, Wq0 + l*256, Wq1 + l*256, q, o0, o1, den, mx);
    k_logit<<<NE/256, 256, 0, stream>>>(m, q, dst, logit, mx);
    k_attnz<<<NE/256, 256, 0, stream>>>(logit, mx, dst, den);
    k_agg<<<NE/256, 256, 0, stream>>>(logit, den, m, dst, o0, o1);
    k_update<<<NN*32/256, 256, 0, stream>>>(o0, o1, f0c, f1c, Wp0 + l*1280, Wp1 + l*1280,
                                            ng0 + l*32, nb0 + l*32, ng1 + l*32, nb1 + l*32,
                                            f0n, f1n);
    f0c = f0n; f1c = f1n; f0n = f0b; f1n = f1b;
  }
  k_radial<<<NE*64/256, 256, 0, stream>>>(es, fW1, fb1, fg, fbe, hbf);
  hipMemsetAsync(d_out, 0, (size_t)out_size*sizeof(float), stream);
  k_fconv_mfma<<<NE/EB, 256, 0, stream>>>(hbf, w2sf, f0c, f1c, rhat, scale, src, dst, (float*)d_out);
}

// Round 8
// 495.657 us; speedup vs baseline: 1.9608x; 1.6585x over previous
//
#include <hip/hip_runtime.h>
#include <math.h>

#define NN 8192
#define NE 32768
#define CC 32
#define EB 32

typedef __attribute__((ext_vector_type(8))) short s16x8;
typedef __attribute__((ext_vector_type(4))) float f32x4;

__device__ __forceinline__ unsigned enc_f(float f) {
  unsigned u = __float_as_uint(f);
  return (u & 0x80000000u) ? ~u : (u | 0x80000000u);
}
__device__ __forceinline__ float dec_f(unsigned u) {
  return (u & 0x80000000u) ? __uint_as_float(u & 0x7FFFFFFFu) : __uint_as_float(~u);
}
__device__ __forceinline__ unsigned short f2bf(float f) {
  unsigned u = __float_as_uint(f);
  u += 0x7FFFu + ((u >> 16) & 1u);
  return (unsigned short)(u >> 16);
}

// ---------------- edge preprocessing ----------------
__global__ void k_prep(const float* __restrict__ rel, const float* __restrict__ ef,
                       float* __restrict__ es, float* __restrict__ rhat) {
  int e = blockIdx.x * blockDim.x + threadIdx.x;
  if (e >= NE) return;
  float x = rel[e*3+0], y = rel[e*3+1], z = rel[e*3+2];
  float rn = sqrtf(x*x + y*y + z*z);
  float inv = 1.0f / (rn + 1e-12f);
  rhat[e*3+0] = x*inv; rhat[e*3+1] = y*inv; rhat[e*3+2] = z*inv;
  es[e*5+0] = rn;
  es[e*5+1] = ef[e*4+0];
  es[e*5+2] = ef[e*4+1];
  es[e*5+3] = ef[e*4+2];
  es[e*5+4] = ef[e*4+3];
}

// ---------------- radial hidden -> bf16 ----------------
__global__ void k_radial(const float* __restrict__ es, const float* __restrict__ W1,
                         const float* __restrict__ b1, const float* __restrict__ g,
                         const float* __restrict__ be, unsigned short* __restrict__ h) {
  int t = blockIdx.x * blockDim.x + threadIdx.x;
  int e = t >> 6, m = t & 63;
  if (e >= NE) return;
  const float* ep = es + (size_t)e*5;
  float v = b1[m];
  v = fmaf(ep[0], W1[0*64+m], v);
  v = fmaf(ep[1], W1[1*64+m], v);
  v = fmaf(ep[2], W1[2*64+m], v);
  v = fmaf(ep[3], W1[3*64+m], v);
  v = fmaf(ep[4], W1[4*64+m], v);
  float s = v;
  #pragma unroll
  for (int off = 32; off; off >>= 1) s += __shfl_xor(s, off);
  float mu = s * (1.0f/64.0f);
  float d = v - mu;
  float s2 = d*d;
  #pragma unroll
  for (int off = 32; off; off >>= 1) s2 += __shfl_xor(s2, off);
  float hv = d * rsqrtf(s2*(1.0f/64.0f) + 1e-5f) * g[m] + be[m];
  h[(size_t)e*64+m] = f2bf(fmaxf(hv, 0.0f));
}

// ---------------- W2 -> bf16 swizzled into B-fragment order ----------------
// dst[((t*2+s)*64 + lane)*8 + j] = bf16( W2[ s*32 + (lane>>4)*8 + j ][ t*16 + (lane&15) ] )
__global__ void k_w2cvt(const float* __restrict__ W2, unsigned short* __restrict__ dstp, int N) {
  int idx = blockIdx.x * blockDim.x + threadIdx.x;
  int total = (N >> 4) * 128;  // (N/16)*2*64
  if (idx >= total) return;
  int l = idx & 63;
  int s = (idx >> 6) & 1;
  int t = idx >> 7;
  int kb = s*32 + (l >> 4)*8;
  int col = t*16 + (l & 15);
  s16x8 v;
  #pragma unroll
  for (int j = 0; j < 8; ++j) v[j] = (short)f2bf(W2[(size_t)(kb + j)*N + col]);
  *reinterpret_cast<s16x8*>(dstp + (size_t)idx*8) = v;
}

// ---------------- fused conv via MFMA: barrier-free, wave-owned column groups ----------------
// m layout per edge (64 floats): [0..15]=m0, [16 + o*3 + a]=m1[o][a]
// wave wv handles 32-col groups g = i*4+wv; macc index ownership == (o & 3) == wv -> plain LDS +=
__global__ __launch_bounds__(256) void k_conv_mfma(
    const unsigned short* __restrict__ hbf, const unsigned short* __restrict__ w2s,
    const float* __restrict__ f0, const float* __restrict__ f1,
    const float* __restrict__ rhat, const float* __restrict__ scale,
    const int* __restrict__ src, float* __restrict__ m_out)
{
  __shared__ __align__(16) float f0s[EB][36];
  __shared__ __align__(16) float t1s[EB][36];
  __shared__ __align__(16) float f1s[EB][100];
  __shared__ __align__(16) float rhs[EB][4];
  __shared__ float scs[EB];
  __shared__ __align__(16) float macc[EB][81];   // stride 81: bank-conflict-free RMW
  __shared__ __align__(16) float Rl[4][32][36];  // per-wave [col][row] R-tile
  int tid = threadIdx.x;
  int e0 = blockIdx.x * EB;

  for (int idx = tid; idx < EB; idx += 256) {
    rhs[idx][0] = rhat[(e0+idx)*3+0];
    rhs[idx][1] = rhat[(e0+idx)*3+1];
    rhs[idx][2] = rhat[(e0+idx)*3+2];
    scs[idx]    = scale[e0+idx];
  }
  for (int idx = tid; idx < EB*80; idx += 256) macc[idx/80][idx%80] = 0.0f;
  for (int idx = tid; idx < EB*CC; idx += 256) {
    int e = idx >> 5, c = idx & 31;
    int sn = src[e0+e];
    f0s[e][c] = f0[(size_t)sn*32 + c];
    float a0 = f1[(size_t)sn*96 + c*3 + 0];
    float a1 = f1[(size_t)sn*96 + c*3 + 1];
    float a2 = f1[(size_t)sn*96 + c*3 + 2];
    f1s[e][c*3+0] = a0; f1s[e][c*3+1] = a1; f1s[e][c*3+2] = a2;
    float rx = rhat[(e0+e)*3+0], ry = rhat[(e0+e)*3+1], rz = rhat[(e0+e)*3+2];
    t1s[e][c] = a0*rx + a1*ry + a2*rz;
  }

  int lane = tid & 63, wv = tid >> 6;
  int cl = lane & 15, rb = (lane >> 4) << 2;   // MFMA D mapping
  int le = lane & 31, hh = lane >> 5;          // epilogue mapping
  // A fragments: lane holds h[row][k0..k0+7], row=lane&15 (+16), k0=(lane>>4)*8 (+32)
  s16x8 af00, af01, af10, af11;
  {
    const unsigned short* hb = hbf + (size_t)e0*64;
    int row = lane & 15;
    int ko  = (lane >> 4) * 8;
    af00 = *reinterpret_cast<const s16x8*>(hb + (size_t)row*64 + ko);
    af01 = *reinterpret_cast<const s16x8*>(hb + (size_t)row*64 + 32 + ko);
    af10 = *reinterpret_cast<const s16x8*>(hb + (size_t)(row+16)*64 + ko);
    af11 = *reinterpret_cast<const s16x8*>(hb + (size_t)(row+16)*64 + 32 + ko);
  }
  __syncthreads();

  const float inv_s3 = 0.57735026919f;
  const float inv_s2 = 0.70710678118f;
  const float c15    = 1.22474487139f;
  float (*Rw)[36] = Rl[wv];

  for (int i = 0; i < 24; ++i) {
    int g = i*4 + wv;                          // 32-col group, 0..95
    const s16x8* bp = reinterpret_cast<const s16x8*>(w2s) + ((size_t)g*4*64 + lane);
    s16x8 b00 = bp[0];     // tile 2g,   k 0..31
    s16x8 b01 = bp[64];    // tile 2g,   k 32..63
    s16x8 b10 = bp[128];   // tile 2g+1, k 0..31
    s16x8 b11 = bp[192];   // tile 2g+1, k 32..63
    f32x4 aA0 = {0.f,0.f,0.f,0.f}, aA1 = {0.f,0.f,0.f,0.f};
    f32x4 aB0 = {0.f,0.f,0.f,0.f}, aB1 = {0.f,0.f,0.f,0.f};
    aA0 = __builtin_amdgcn_mfma_f32_16x16x32_bf16(af00, b00, aA0, 0,0,0);
    aA0 = __builtin_amdgcn_mfma_f32_16x16x32_bf16(af01, b01, aA0, 0,0,0);
    aA1 = __builtin_amdgcn_mfma_f32_16x16x32_bf16(af10, b00, aA1, 0,0,0);
    aA1 = __builtin_amdgcn_mfma_f32_16x16x32_bf16(af11, b01, aA1, 0,0,0);
    aB0 = __builtin_amdgcn_mfma_f32_16x16x32_bf16(af00, b10, aB0, 0,0,0);
    aB0 = __builtin_amdgcn_mfma_f32_16x16x32_bf16(af01, b11, aB0, 0,0,0);
    aB1 = __builtin_amdgcn_mfma_f32_16x16x32_bf16(af10, b10, aB1, 0,0,0);
    aB1 = __builtin_amdgcn_mfma_f32_16x16x32_bf16(af11, b11, aB1, 0,0,0);
    // stage wave-private R-tile [col][row] (16B-aligned f32x4 stores)
    *reinterpret_cast<f32x4*>(&Rw[cl][rb])       = aA0;
    *reinterpret_cast<f32x4*>(&Rw[cl][16+rb])    = aA1;
    *reinterpret_cast<f32x4*>(&Rw[16+cl][rb])    = aB0;
    *reinterpret_cast<f32x4*>(&Rw[16+cl][16+rb]) = aB1;
    // same-wave epilogue: lane = (edge le, col-half hh)
    float r16[16];
    #pragma unroll
    for (int j = 0; j < 16; ++j) r16[j] = Rw[hh*16 + j][le];
    if (g < 32) {                              // R00 (g<16) -> m0[g]; R01 -> q01 at idx g
      const float* fp = &f0s[le][hh*16];
      float p = 0.f;
      #pragma unroll
      for (int j = 0; j < 16; ++j) p = fmaf(r16[j], fp[j], p);
      p += __shfl_xor(p, 32);
      if (hh == 0) macc[le][g] += p;
    } else if (g < 48) {                       // R10 -> m0[g-32]
      const float* tp = &t1s[le][hh*16];
      float p = 0.f;
      #pragma unroll
      for (int j = 0; j < 16; ++j) p = fmaf(r16[j], tp[j], p);
      p += __shfl_xor(p, 32);
      if (hh == 0) macc[le][g-32] += p;
    } else {                                   // R11: reduce V=sum R*f1, W=sum R*t1, transform after
      int gg = g - 48, j3 = gg >> 4, o = gg & 15;
      const float* f1p = &f1s[le][hh*48];
      float v0 = 0.f, v1 = 0.f, v2 = 0.f, w = 0.f;
      #pragma unroll
      for (int j = 0; j < 16; ++j) {
        float r = r16[j];
        v0 = fmaf(r, f1p[j*3+0], v0);
        v1 = fmaf(r, f1p[j*3+1], v1);
        v2 = fmaf(r, f1p[j*3+2], v2);
      }
      if (j3 == 2) {
        const float* tp = &t1s[le][hh*16];
        #pragma unroll
        for (int j = 0; j < 16; ++j) w = fmaf(r16[j], tp[j], w);
      }
      v0 += __shfl_xor(v0, 32);
      v1 += __shfl_xor(v1, 32);
      v2 += __shfl_xor(v2, 32);
      if (j3 == 2) w += __shfl_xor(w, 32);
      if (hh == 0) {
        float u0, u1, u2;
        if (j3 == 0) {
          u0 = v0*inv_s3; u1 = v1*inv_s3; u2 = v2*inv_s3;
        } else if (j3 == 1) {
          float rx = rhs[le][0], ry = rhs[le][1], rz = rhs[le][2];
          u0 = (rz*v1 - ry*v2)*inv_s2;
          u1 = (rx*v2 - rz*v0)*inv_s2;
          u2 = (ry*v0 - rx*v1)*inv_s2;
        } else {
          float rx = rhs[le][0], ry = rhs[le][1], rz = rhs[le][2];
          u0 = c15*(rx*w - v0*(1.0f/3.0f));
          u1 = c15*(ry*w - v1*(1.0f/3.0f));
          u2 = c15*(rz*w - v2*(1.0f/3.0f));
        }
        macc[le][32 + o*3 + 0] += u0;
        macc[le][32 + o*3 + 1] += u1;
        macc[le][32 + o*3 + 2] += u2;
      }
    }
  }
  __syncthreads();
  for (int idx = tid; idx < EB*64; idx += 256) {
    int e = idx >> 6, t2 = idx & 63;
    float sc = scs[e];
    float val;
    if (t2 < 16) {
      val = macc[e][t2] * sc;
    } else {
      int o = (t2-16)/3, a2 = (t2-16)%3;
      val = (macc[e][32 + (t2-16)] + macc[e][16+o]*rhs[e][a2]) * sc;
    }
    m_out[(size_t)(e0+e)*64 + t2] = val;
  }
}

// ---------------- queries + zero attention accumulators ----------------
__global__ void k_query(const float* __restrict__ f0, const float* __restrict__ f1,
                        const float* __restrict__ Wq0, const float* __restrict__ Wq1,
                        float* __restrict__ q, float* __restrict__ o0, float* __restrict__ o1,
                        float* __restrict__ den, unsigned* __restrict__ mx) {
  int n = blockIdx.x * blockDim.x + threadIdx.x;
  if (n >= NN) return;
  float q0[8]  = {0,0,0,0,0,0,0,0};
  float q1x[8] = {0,0,0,0,0,0,0,0};
  float q1y[8] = {0,0,0,0,0,0,0,0};
  float q1z[8] = {0,0,0,0,0,0,0,0};
  for (int c = 0; c < 32; ++c) {
    float fv = f0[(size_t)n*32+c];
    float fx = f1[(size_t)n*96+c*3+0];
    float fy = f1[(size_t)n*96+c*3+1];
    float fz = f1[(size_t)n*96+c*3+2];
    #pragma unroll
    for (int k = 0; k < 8; ++k) {
      float w0 = Wq0[c*8+k], w1 = Wq1[c*8+k];
      q0[k]  = fmaf(fv, w0, q0[k]);
      q1x[k] = fmaf(fx, w1, q1x[k]);
      q1y[k] = fmaf(fy, w1, q1y[k]);
      q1z[k] = fmaf(fz, w1, q1z[k]);
    }
  }
  #pragma unroll
  for (int k = 0; k < 8; ++k) {
    q[(size_t)n*32+k]         = q0[k];
    q[(size_t)n*32+8+k*3+0]   = q1x[k];
    q[(size_t)n*32+8+k*3+1]   = q1y[k];
    q[(size_t)n*32+8+k*3+2]   = q1z[k];
    o0[(size_t)n*8+k] = 0.0f; den[(size_t)n*8+k] = 0.0f; mx[(size_t)n*8+k] = 0u;
  }
  #pragma unroll
  for (int i = 0; i < 24; ++i) o1[(size_t)n*24+i] = 0.0f;
}

// ---------------- attention pass 1 ----------------
__global__ void k_logit(const float* __restrict__ m, const float* __restrict__ q,
                        const int* __restrict__ dst, float* __restrict__ logit,
                        unsigned* __restrict__ mx) {
  int e = blockIdx.x * blockDim.x + threadIdx.x;
  if (e >= NE) return;
  int d = dst[e];
  const float* me = m + (size_t)e*64;
  const float* qd = q + (size_t)d*32;
  #pragma unroll
  for (int hh = 0; hh < 8; ++hh) {
    float l = 0.0f;
    #pragma unroll
    for (int t = 0; t < 4; ++t) {
      int col = hh*4 + t;
      float kv = (col < 8) ? me[col] : me[16 + (col-8)];
      l = fmaf(kv, qd[col], l);
    }
    l *= 0.5f;
    logit[(size_t)e*8+hh] = l;
    atomicMax(&mx[(size_t)d*8+hh], enc_f(l));
  }
}

// ---------------- attention pass 2 ----------------
__global__ void k_attnz(float* __restrict__ logit, const unsigned* __restrict__ mx,
                        const int* __restrict__ dst, float* __restrict__ den) {
  int e = blockIdx.x * blockDim.x + threadIdx.x;
  if (e >= NE) return;
  int d = dst[e];
  #pragma unroll
  for (int hh = 0; hh < 8; ++hh) {
    float mv = dec_f(mx[(size_t)d*8+hh]);
    float z = expf(logit[(size_t)e*8+hh] - mv);
    logit[(size_t)e*8+hh] = z;
    atomicAdd(&den[(size_t)d*8+hh], z);
  }
}

// ---------------- attention pass 3 ----------------
__global__ void k_agg(const float* __restrict__ z, const float* __restrict__ den,
                      const float* __restrict__ m, const int* __restrict__ dst,
                      float* __restrict__ o0, float* __restrict__ o1) {
  int e = blockIdx.x * blockDim.x + threadIdx.x;
  if (e >= NE) return;
  int d = dst[e];
  const float* me = m + (size_t)e*64;
  #pragma unroll
  for (int hh = 0; hh < 8; ++hh) {
    float a = z[(size_t)e*8+hh] / (den[(size_t)d*8+hh] + 1e-9f);
    atomicAdd(&o0[(size_t)d*8+hh], a * me[8+hh]);
    #pragma unroll
    for (int a2 = 0; a2 < 3; ++a2)
      atomicAdd(&o1[(size_t)d*24 + hh*3 + a2], a * me[16 + (8+hh)*3 + a2]);
  }
}

// ---------------- projection + NormSE3 ----------------
__global__ void k_update(const float* __restrict__ o0, const float* __restrict__ o1,
                         const float* __restrict__ f0c, const float* __restrict__ f1c,
                         const float* __restrict__ Wp0, const float* __restrict__ Wp1,
                         const float* __restrict__ ng0v, const float* __restrict__ nb0v,
                         const float* __restrict__ ng1v, const float* __restrict__ nb1v,
                         float* __restrict__ f0o, float* __restrict__ f1o) {
  int t = blockIdx.x * blockDim.x + threadIdx.x;
  int n = t >> 5, o = t & 31;
  if (n >= NN) return;
  float a0 = 0.0f, ax = 0.0f, ay = 0.0f, az = 0.0f;
  for (int c = 0; c < 8; ++c) {
    float w0 = Wp0[c*32+o], w1 = Wp1[c*32+o];
    a0 = fmaf(o0[(size_t)n*8+c], w0, a0);
    ax = fmaf(o1[(size_t)n*24+c*3+0], w1, ax);
    ay = fmaf(o1[(size_t)n*24+c*3+1], w1, ay);
    az = fmaf(o1[(size_t)n*24+c*3+2], w1, az);
  }
  for (int c = 0; c < 32; ++c) {
    float w0 = Wp0[(8+c)*32+o], w1 = Wp1[(8+c)*32+o];
    a0 = fmaf(f0c[(size_t)n*32+c], w0, a0);
    ax = fmaf(f1c[(size_t)n*96+c*3+0], w1, ax);
    ay = fmaf(f1c[(size_t)n*96+c*3+1], w1, ay);
    az = fmaf(f1c[(size_t)n*96+c*3+2], w1, az);
  }
  float nn0 = sqrtf(a0*a0 + 1e-12f);
  float nn1 = sqrtf(ax*ax + ay*ay + az*az + 1e-12f);
  float s0 = nn0, s1 = nn1;
  #pragma unroll
  for (int off = 16; off; off >>= 1) { s0 += __shfl_xor(s0, off, 32); s1 += __shfl_xor(s1, off, 32); }
  float mu0 = s0*(1.0f/32.0f), mu1 = s1*(1.0f/32.0f);
  float d0 = nn0 - mu0, d1 = nn1 - mu1;
  float v0 = d0*d0, v1 = d1*d1;
  #pragma unroll
  for (int off = 16; off; off >>= 1) { v0 += __shfl_xor(v0, off, 32); v1 += __shfl_xor(v1, off, 32); }
  float g0 = fmaxf(d0*rsqrtf(v0*(1.0f/32.0f)+1e-5f)*ng0v[o] + nb0v[o], 0.0f) / nn0;
  float g1 = fmaxf(d1*rsqrtf(v1*(1.0f/32.0f)+1e-5f)*ng1v[o] + nb1v[o], 0.0f) / nn1;
  f0o[(size_t)n*32+o] = a0*g0;
  f1o[(size_t)n*96+o*3+0] = ax*g1;
  f1o[(size_t)n*96+o*3+1] = ay*g1;
  f1o[(size_t)n*96+o*3+2] = az*g1;
}

// ---------------- final conv via MFMA (barrier-free) -> scatter ----------------
__global__ __launch_bounds__(256) void k_fconv_mfma(
    const unsigned short* __restrict__ hbf, const unsigned short* __restrict__ w2s,
    const float* __restrict__ f0, const float* __restrict__ f1,
    const float* __restrict__ rhat, const float* __restrict__ scale,
    const int* __restrict__ src, const int* __restrict__ dst, float* __restrict__ out)
{
  __shared__ __align__(16) float f0s[EB][36];
  __shared__ __align__(16) float t1s[EB][36];
  __shared__ float macc[EB][17];
  __shared__ float scs[EB];
  __shared__ __align__(16) float Rl[4][32][36];
  int tid = threadIdx.x;
  int e0 = blockIdx.x * EB;

  for (int idx = tid; idx < EB; idx += 256) scs[idx] = scale[e0+idx];
  for (int idx = tid; idx < EB*16; idx += 256) macc[idx>>4][idx&15] = 0.0f;
  for (int idx = tid; idx < EB*CC; idx += 256) {
    int e = idx >> 5, c = idx & 31;
    int sn = src[e0+e];
    f0s[e][c] = f0[(size_t)sn*32 + c];
    float a0 = f1[(size_t)sn*96 + c*3 + 0];
    float a1 = f1[(size_t)sn*96 + c*3 + 1];
    float a2 = f1[(size_t)sn*96 + c*3 + 2];
    float rx = rhat[(e0+e)*3+0], ry = rhat[(e0+e)*3+1], rz = rhat[(e0+e)*3+2];
    t1s[e][c] = a0*rx + a1*ry + a2*rz;
  }
  int lane = tid & 63, wv = tid >> 6;
  int cl = lane & 15, rb = (lane >> 4) << 2;
  int le = lane & 31, hh = lane >> 5;
  s16x8 af00, af01, af10, af11;
  {
    const unsigned short* hb = hbf + (size_t)e0*64;
    int row = lane & 15;
    int ko  = (lane >> 4) * 8;
    af00 = *reinterpret_cast<const s16x8*>(hb + (size_t)row*64 + ko);
    af01 = *reinterpret_cast<const s16x8*>(hb + (size_t)row*64 + 32 + ko);
    af10 = *reinterpret_cast<const s16x8*>(hb + (size_t)(row+16)*64 + ko);
    af11 = *reinterpret_cast<const s16x8*>(hb + (size_t)(row+16)*64 + 32 + ko);
  }
  __syncthreads();
  float (*Rw)[36] = Rl[wv];

  for (int i = 0; i < 8; ++i) {
    int g = i*4 + wv;                          // 0..31
    const s16x8* bp = reinterpret_cast<const s16x8*>(w2s) + ((size_t)g*4*64 + lane);
    s16x8 b00 = bp[0];
    s16x8 b01 = bp[64];
    s16x8 b10 = bp[128];
    s16x8 b11 = bp[192];
    f32x4 aA0 = {0.f,0.f,0.f,0.f}, aA1 = {0.f,0.f,0.f,0.f};
    f32x4 aB0 = {0.f,0.f,0.f,0.f}, aB1 = {0.f,0.f,0.f,0.f};
    aA0 = __builtin_amdgcn_mfma_f32_16x16x32_bf16(af00, b00, aA0, 0,0,0);
    aA0 = __builtin_amdgcn_mfma_f32_16x16x32_bf16(af01, b01, aA0, 0,0,0);
    aA1 = __builtin_amdgcn_mfma_f32_16x16x32_bf16(af10, b00, aA1, 0,0,0);
    aA1 = __builtin_amdgcn_mfma_f32_16x16x32_bf16(af11, b01, aA1, 0,0,0);
    aB0 = __builtin_amdgcn_mfma_f32_16x16x32_bf16(af00, b10, aB0, 0,0,0);
    aB0 = __builtin_amdgcn_mfma_f32_16x16x32_bf16(af01, b11, aB0, 0,0,0);
    aB1 = __builtin_amdgcn_mfma_f32_16x16x32_bf16(af10, b10, aB1, 0,0,0);
    aB1 = __builtin_amdgcn_mfma_f32_16x16x32_bf16(af11, b11, aB1, 0,0,0);
    *reinterpret_cast<f32x4*>(&Rw[cl][rb])       = aA0;
    *reinterpret_cast<f32x4*>(&Rw[cl][16+rb])    = aA1;
    *reinterpret_cast<f32x4*>(&Rw[16+cl][rb])    = aB0;
    *reinterpret_cast<f32x4*>(&Rw[16+cl][16+rb]) = aB1;
    float r16[16];
    #pragma unroll
    for (int j = 0; j < 16; ++j) r16[j] = Rw[hh*16 + j][le];
    const float* mp = (g < 16) ? &f0s[le][hh*16] : &t1s[le][hh*16];
    float p = 0.f;
    #pragma unroll
    for (int j = 0; j < 16; ++j) p = fmaf(r16[j], mp[j], p);
    p += __shfl_xor(p, 32);
    if (hh == 0) macc[le][g & 15] += p;
  }
  __syncthreads();
  for (int idx = tid; idx < EB*16; idx += 256) {
    int e = idx >> 4, o = idx & 15;
    atomicAdd(&out[(size_t)dst[e0+e]*16 + o], macc[e][o]*scs[e]);
  }
}

extern "C" void kernel_launch(void* const* d_in, const int* in_sizes, int n_in,
                              void* d_out, int out_size, void* d_ws, size_t ws_size,
                              hipStream_t stream) {
  (void)in_sizes; (void)n_in; (void)ws_size;
  const float* nf0  = (const float*)d_in[0];
  const float* nf1  = (const float*)d_in[1];
  const float* ef0  = (const float*)d_in[2];
  const float* rel  = (const float*)d_in[3];
  const float* scale= (const float*)d_in[4];
  const int*   src  = (const int*)d_in[5];
  const int*   dst  = (const int*)d_in[6];
  const float* rW1  = (const float*)d_in[7];
  const float* rb1  = (const float*)d_in[8];
  const float* rg   = (const float*)d_in[9];
  const float* rbe  = (const float*)d_in[10];
  const float* rW2  = (const float*)d_in[11];
  const float* Wq0  = (const float*)d_in[12];
  const float* Wq1  = (const float*)d_in[13];
  const float* Wp0  = (const float*)d_in[14];
  const float* Wp1  = (const float*)d_in[15];
  const float* ng0  = (const float*)d_in[16];
  const float* nb0  = (const float*)d_in[17];
  const float* ng1  = (const float*)d_in[18];
  const float* nb1  = (const float*)d_in[19];
  const float* fW1  = (const float*)d_in[20];
  const float* fb1  = (const float*)d_in[21];
  const float* fg   = (const float*)d_in[22];
  const float* fbe  = (const float*)d_in[23];
  const float* fW2  = (const float*)d_in[24];

  float* ws = (float*)d_ws;
  size_t off = 0;
  float* es    = ws + off; off += (size_t)NE*5;
  float* rhat  = ws + off; off += (size_t)NE*3;
  float* m     = ws + off; off += (size_t)NE*64;
  float* q     = ws + off; off += (size_t)NN*32;
  float* logit = ws + off; off += (size_t)NE*8;
  unsigned* mx = (unsigned*)(ws + off); off += (size_t)NN*8;
  float* den   = ws + off; off += (size_t)NN*8;
  float* o0    = ws + off; off += (size_t)NN*8;
  float* o1    = ws + off; off += (size_t)NN*24;
  float* f0a   = ws + off; off += (size_t)NN*32;
  float* f1a   = ws + off; off += (size_t)NN*96;
  float* f0b   = ws + off; off += (size_t)NN*32;
  float* f1b   = ws + off; off += (size_t)NN*96;
  unsigned short* usbase = (unsigned short*)(ws + off);
  unsigned short* hbf  = usbase;                               // NE*64
  unsigned short* w2s0 = hbf  + (size_t)NE*64;                 // 192*2*64*8 = 196608
  unsigned short* w2s1 = w2s0 + 196608;
  unsigned short* w2sf = w2s1 + 196608;                        // 64*2*64*8 = 65536

  // weight pre-swizzle (bf16 B-fragment order), once per launch
  k_w2cvt<<<96, 256, 0, stream>>>(rW2,            w2s0, 3072);
  k_w2cvt<<<96, 256, 0, stream>>>(rW2 + 64*3072,  w2s1, 3072);
  k_w2cvt<<<32, 256, 0, stream>>>(fW2,            w2sf, 1024);

  k_prep<<<NE/256, 256, 0, stream>>>(rel, ef0, es, rhat);

  const float* f0c = nf0; const float* f1c = nf1;
  float* f0n = f0a; float* f1n = f1a;
  for (int l = 0; l < 2; ++l) {
    k_radial<<<NE*64/256, 256, 0, stream>>>(es, rW1 + l*320, rb1 + l*64, rg + l*64, rbe + l*64, hbf);
    k_conv_mfma<<<NE/EB, 256, 0, stream>>>(hbf, (l == 0) ? w2s0 : w2s1, f0c, f1c, rhat, scale, src, m);
    k_query<<<NN/256, 256, 0, stream>>>(f0c, f1c, Wq0 + l*256, Wq1 + l*256, q, o0, o1, den, mx);
    k_logit<<<NE/256, 256, 0, stream>>>(m, q, dst, logit, mx);
    k_attnz<<<NE/256, 256, 0, stream>>>(logit, mx, dst, den);
    k_agg<<<NE/256, 256, 0, stream>>>(logit, den, m, dst, o0, o1);
    k_update<<<NN*32/256, 256, 0, stream>>>(o0, o1, f0c, f1c, Wp0 + l*1280, Wp1 + l*1280,
                                            ng0 + l*32, nb0 + l*32, ng1 + l*32, nb1 + l*32,
                                            f0n, f1n);
    f0c = f0n; f1c = f1n; f0n = f0b; f1n = f1b;
  }
  k_radial<<<NE*64/256, 256, 0, stream>>>(es, fW1, fb1, fg, fbe, hbf);
  hipMemsetAsync(d_out, 0, (size_t)out_size*sizeof(float), stream);
  k_fconv_mfma<<<NE/EB, 256, 0, stream>>>(hbf, w2sf, f0c, f1c, rhat, scale, src, dst, (float*)d_out);
}

// Round 9
// 340.274 us; speedup vs baseline: 2.8562x; 1.4566x over previous
//
#include <hip/hip_runtime.h>
#include <math.h>

#define NN 8192
#define NE 32768
#define CC 32
#define EB 32

typedef __attribute__((ext_vector_type(8))) short s16x8;
typedef __attribute__((ext_vector_type(4))) float f32x4;

__device__ __forceinline__ unsigned short f2bf(float f) {
  unsigned u = __float_as_uint(f);
  u += 0x7FFFu + ((u >> 16) & 1u);
  return (unsigned short)(u >> 16);
}

// ---------------- edge preprocessing ----------------
__global__ void k_prep(const float* __restrict__ rel, const float* __restrict__ ef,
                       float* __restrict__ es, float* __restrict__ rhat) {
  int e = blockIdx.x * blockDim.x + threadIdx.x;
  if (e >= NE) return;
  float x = rel[e*3+0], y = rel[e*3+1], z = rel[e*3+2];
  float rn = sqrtf(x*x + y*y + z*z);
  float inv = 1.0f / (rn + 1e-12f);
  rhat[e*3+0] = x*inv; rhat[e*3+1] = y*inv; rhat[e*3+2] = z*inv;
  es[e*5+0] = rn;
  es[e*5+1] = ef[e*4+0];
  es[e*5+2] = ef[e*4+1];
  es[e*5+3] = ef[e*4+2];
  es[e*5+4] = ef[e*4+3];
}

// ---------------- CSR build over dst ----------------
__global__ void k_count(const int* __restrict__ dst, int* __restrict__ cnt) {
  int e = blockIdx.x * blockDim.x + threadIdx.x;
  if (e < NE) atomicAdd(&cnt[dst[e]], 1);
}

__global__ __launch_bounds__(1024) void k_scan(const int* __restrict__ cnt,
                                               int* __restrict__ offs, int* __restrict__ cursor) {
  __shared__ int part[1024];
  int t = threadIdx.x;
  int base = t * 8;
  int loc[8];
  int s = 0;
  #pragma unroll
  for (int j = 0; j < 8; ++j) { loc[j] = s; s += cnt[base + j]; }
  part[t] = s;
  __syncthreads();
  for (int off = 1; off < 1024; off <<= 1) {
    int v = (t >= off) ? part[t - off] : 0;
    __syncthreads();
    part[t] += v;
    __syncthreads();
  }
  int pre = (t == 0) ? 0 : part[t - 1];
  #pragma unroll
  for (int j = 0; j < 8; ++j) {
    int o = pre + loc[j];
    offs[base + j] = o;
    cursor[base + j] = o;
  }
  if (t == 1023) offs[NN] = part[1023];
}

__global__ void k_fill(const int* __restrict__ dst, int* __restrict__ cursor,
                       int* __restrict__ eidx) {
  int e = blockIdx.x * blockDim.x + threadIdx.x;
  if (e >= NE) return;
  int pos = atomicAdd(&cursor[dst[e]], 1);
  eidx[pos] = e;
}

// ---------------- radial hidden -> bf16 ----------------
__global__ void k_radial(const float* __restrict__ es, const float* __restrict__ W1,
                         const float* __restrict__ b1, const float* __restrict__ g,
                         const float* __restrict__ be, unsigned short* __restrict__ h) {
  int t = blockIdx.x * blockDim.x + threadIdx.x;
  int e = t >> 6, m = t & 63;
  if (e >= NE) return;
  const float* ep = es + (size_t)e*5;
  float v = b1[m];
  v = fmaf(ep[0], W1[0*64+m], v);
  v = fmaf(ep[1], W1[1*64+m], v);
  v = fmaf(ep[2], W1[2*64+m], v);
  v = fmaf(ep[3], W1[3*64+m], v);
  v = fmaf(ep[4], W1[4*64+m], v);
  float s = v;
  #pragma unroll
  for (int off = 32; off; off >>= 1) s += __shfl_xor(s, off);
  float mu = s * (1.0f/64.0f);
  float d = v - mu;
  float s2 = d*d;
  #pragma unroll
  for (int off = 32; off; off >>= 1) s2 += __shfl_xor(s2, off);
  float hv = d * rsqrtf(s2*(1.0f/64.0f) + 1e-5f) * g[m] + be[m];
  h[(size_t)e*64+m] = f2bf(fmaxf(hv, 0.0f));
}

// ---------------- W2 -> bf16 swizzled into B-fragment order ----------------
__global__ void k_w2cvt(const float* __restrict__ W2, unsigned short* __restrict__ dstp, int N) {
  int idx = blockIdx.x * blockDim.x + threadIdx.x;
  int total = (N >> 4) * 128;
  if (idx >= total) return;
  int l = idx & 63;
  int s = (idx >> 6) & 1;
  int t = idx >> 7;
  int kb = s*32 + (l >> 4)*8;
  int col = t*16 + (l & 15);
  s16x8 v;
  #pragma unroll
  for (int j = 0; j < 8; ++j) v[j] = (short)f2bf(W2[(size_t)(kb + j)*N + col]);
  *reinterpret_cast<s16x8*>(dstp + (size_t)idx*8) = v;
}

// ---------------- fused conv via MFMA: barrier-free, odd-stride LDS ----------------
// m layout per edge (64 floats): [0..15]=m0, [16 + o*3 + a]=m1[o][a]
__global__ __launch_bounds__(256) void k_conv_mfma(
    const unsigned short* __restrict__ hbf, const unsigned short* __restrict__ w2s,
    const float* __restrict__ f0, const float* __restrict__ f1,
    const float* __restrict__ rhat, const float* __restrict__ scale,
    const int* __restrict__ src, float* __restrict__ m_out)
{
  __shared__ float f0s[EB][33];
  __shared__ float t1s[EB][33];
  __shared__ float f1s[EB][99];
  __shared__ float rhs[EB][4];
  __shared__ float scs[EB];
  __shared__ float macc[EB][81];
  __shared__ float Rl[4][32][33];   // per-wave [col][row], odd stride
  int tid = threadIdx.x;
  int e0 = blockIdx.x * EB;

  for (int idx = tid; idx < EB; idx += 256) {
    rhs[idx][0] = rhat[(e0+idx)*3+0];
    rhs[idx][1] = rhat[(e0+idx)*3+1];
    rhs[idx][2] = rhat[(e0+idx)*3+2];
    scs[idx]    = scale[e0+idx];
  }
  for (int idx = tid; idx < EB*80; idx += 256) macc[idx/80][idx%80] = 0.0f;
  for (int idx = tid; idx < EB*CC; idx += 256) {
    int e = idx >> 5, c = idx & 31;
    int sn = src[e0+e];
    f0s[e][c] = f0[(size_t)sn*32 + c];
    float a0 = f1[(size_t)sn*96 + c*3 + 0];
    float a1 = f1[(size_t)sn*96 + c*3 + 1];
    float a2 = f1[(size_t)sn*96 + c*3 + 2];
    f1s[e][c*3+0] = a0; f1s[e][c*3+1] = a1; f1s[e][c*3+2] = a2;
    float rx = rhat[(e0+e)*3+0], ry = rhat[(e0+e)*3+1], rz = rhat[(e0+e)*3+2];
    t1s[e][c] = a0*rx + a1*ry + a2*rz;
  }

  int lane = tid & 63, wv = tid >> 6;
  int cl = lane & 15, rb = (lane >> 4) << 2;   // MFMA D mapping
  int le = lane & 31, hh = lane >> 5;          // epilogue mapping
  s16x8 af00, af01, af10, af11;
  {
    const unsigned short* hb = hbf + (size_t)e0*64;
    int row = lane & 15;
    int ko  = (lane >> 4) * 8;
    af00 = *reinterpret_cast<const s16x8*>(hb + (size_t)row*64 + ko);
    af01 = *reinterpret_cast<const s16x8*>(hb + (size_t)row*64 + 32 + ko);
    af10 = *reinterpret_cast<const s16x8*>(hb + (size_t)(row+16)*64 + ko);
    af11 = *reinterpret_cast<const s16x8*>(hb + (size_t)(row+16)*64 + 32 + ko);
  }
  __syncthreads();

  const float inv_s3 = 0.57735026919f;
  const float inv_s2 = 0.70710678118f;
  const float c15    = 1.22474487139f;
  float (*Rw)[33] = Rl[wv];

  for (int i = 0; i < 24; ++i) {
    int g = i*4 + wv;                          // 32-col group, 0..95
    const s16x8* bp = reinterpret_cast<const s16x8*>(w2s) + ((size_t)g*4*64 + lane);
    s16x8 b00 = bp[0];
    s16x8 b01 = bp[64];
    s16x8 b10 = bp[128];
    s16x8 b11 = bp[192];
    f32x4 aA0 = {0.f,0.f,0.f,0.f}, aA1 = {0.f,0.f,0.f,0.f};
    f32x4 aB0 = {0.f,0.f,0.f,0.f}, aB1 = {0.f,0.f,0.f,0.f};
    aA0 = __builtin_amdgcn_mfma_f32_16x16x32_bf16(af00, b00, aA0, 0,0,0);
    aA0 = __builtin_amdgcn_mfma_f32_16x16x32_bf16(af01, b01, aA0, 0,0,0);
    aA1 = __builtin_amdgcn_mfma_f32_16x16x32_bf16(af10, b00, aA1, 0,0,0);
    aA1 = __builtin_amdgcn_mfma_f32_16x16x32_bf16(af11, b01, aA1, 0,0,0);
    aB0 = __builtin_amdgcn_mfma_f32_16x16x32_bf16(af00, b10, aB0, 0,0,0);
    aB0 = __builtin_amdgcn_mfma_f32_16x16x32_bf16(af01, b11, aB0, 0,0,0);
    aB1 = __builtin_amdgcn_mfma_f32_16x16x32_bf16(af10, b10, aB1, 0,0,0);
    aB1 = __builtin_amdgcn_mfma_f32_16x16x32_bf16(af11, b11, aB1, 0,0,0);
    #pragma unroll
    for (int r = 0; r < 4; ++r) {
      Rw[cl][rb+r]       = aA0[r];
      Rw[cl][16+rb+r]    = aA1[r];
      Rw[16+cl][rb+r]    = aB0[r];
      Rw[16+cl][16+rb+r] = aB1[r];
    }
    // same-wave epilogue: lane = (edge le, col-half hh)
    float r16[16];
    #pragma unroll
    for (int j = 0; j < 16; ++j) r16[j] = Rw[hh*16 + j][le];
    if (g < 32) {
      const float* fp = &f0s[le][hh*16];
      float p = 0.f;
      #pragma unroll
      for (int j = 0; j < 16; ++j) p = fmaf(r16[j], fp[j], p);
      p += __shfl_xor(p, 32);
      if (hh == 0) macc[le][g] += p;
    } else if (g < 48) {
      const float* tp = &t1s[le][hh*16];
      float p = 0.f;
      #pragma unroll
      for (int j = 0; j < 16; ++j) p = fmaf(r16[j], tp[j], p);
      p += __shfl_xor(p, 32);
      if (hh == 0) macc[le][g-32] += p;
    } else {
      int gg = g - 48, j3 = gg >> 4, o = gg & 15;
      const float* f1p = &f1s[le][hh*48];
      float v0 = 0.f, v1 = 0.f, v2 = 0.f, w = 0.f;
      #pragma unroll
      for (int j = 0; j < 16; ++j) {
        float r = r16[j];
        v0 = fmaf(r, f1p[j*3+0], v0);
        v1 = fmaf(r, f1p[j*3+1], v1);
        v2 = fmaf(r, f1p[j*3+2], v2);
      }
      if (j3 == 2) {
        const float* tp = &t1s[le][hh*16];
        #pragma unroll
        for (int j = 0; j < 16; ++j) w = fmaf(r16[j], tp[j], w);
      }
      v0 += __shfl_xor(v0, 32);
      v1 += __shfl_xor(v1, 32);
      v2 += __shfl_xor(v2, 32);
      if (j3 == 2) w += __shfl_xor(w, 32);
      if (hh == 0) {
        float u0, u1, u2;
        if (j3 == 0) {
          u0 = v0*inv_s3; u1 = v1*inv_s3; u2 = v2*inv_s3;
        } else if (j3 == 1) {
          float rx = rhs[le][0], ry = rhs[le][1], rz = rhs[le][2];
          u0 = (rz*v1 - ry*v2)*inv_s2;
          u1 = (rx*v2 - rz*v0)*inv_s2;
          u2 = (ry*v0 - rx*v1)*inv_s2;
        } else {
          float rx = rhs[le][0], ry = rhs[le][1], rz = rhs[le][2];
          u0 = c15*(rx*w - v0*(1.0f/3.0f));
          u1 = c15*(ry*w - v1*(1.0f/3.0f));
          u2 = c15*(rz*w - v2*(1.0f/3.0f));
        }
        macc[le][32 + o*3 + 0] += u0;
        macc[le][32 + o*3 + 1] += u1;
        macc[le][32 + o*3 + 2] += u2;
      }
    }
  }
  __syncthreads();
  for (int idx = tid; idx < EB*64; idx += 256) {
    int e = idx >> 6, t2 = idx & 63;
    float sc = scs[e];
    float val;
    if (t2 < 16) {
      val = macc[e][t2] * sc;
    } else {
      int o = (t2-16)/3, a2 = (t2-16)%3;
      val = (macc[e][32 + (t2-16)] + macc[e][16+o]*rhs[e][a2]) * sc;
    }
    m_out[(size_t)(e0+e)*64 + t2] = val;
  }
}

// ---------------- queries ----------------
__global__ void k_query(const float* __restrict__ f0, const float* __restrict__ f1,
                        const float* __restrict__ Wq0, const float* __restrict__ Wq1,
                        float* __restrict__ q) {
  int n = blockIdx.x * blockDim.x + threadIdx.x;
  if (n >= NN) return;
  float q0[8]  = {0,0,0,0,0,0,0,0};
  float q1x[8] = {0,0,0,0,0,0,0,0};
  float q1y[8] = {0,0,0,0,0,0,0,0};
  float q1z[8] = {0,0,0,0,0,0,0,0};
  for (int c = 0; c < 32; ++c) {
    float fv = f0[(size_t)n*32+c];
    float fx = f1[(size_t)n*96+c*3+0];
    float fy = f1[(size_t)n*96+c*3+1];
    float fz = f1[(size_t)n*96+c*3+2];
    #pragma unroll
    for (int k = 0; k < 8; ++k) {
      float w0 = Wq0[c*8+k], w1 = Wq1[c*8+k];
      q0[k]  = fmaf(fv, w0, q0[k]);
      q1x[k] = fmaf(fx, w1, q1x[k]);
      q1y[k] = fmaf(fy, w1, q1y[k]);
      q1z[k] = fmaf(fz, w1, q1z[k]);
    }
  }
  #pragma unroll
  for (int k = 0; k < 8; ++k) {
    q[(size_t)n*32+k]         = q0[k];
    q[(size_t)n*32+8+k*3+0]   = q1x[k];
    q[(size_t)n*32+8+k*3+1]   = q1y[k];
    q[(size_t)n*32+8+k*3+2]   = q1z[k];
  }
}

// ---------------- attention: CSR gather + online softmax, thread per (node, head) ----------------
__global__ void k_attn(const float* __restrict__ m, const float* __restrict__ q,
                       const int* __restrict__ offs, const int* __restrict__ eidx,
                       float* __restrict__ o0, float* __restrict__ o1) {
  int idx = blockIdx.x * blockDim.x + threadIdx.x;
  int n = idx >> 3, h = idx & 7;
  if (n >= NN) return;
  const float* qd = q + (size_t)n*32 + 4*h;
  float q0 = qd[0], q1 = qd[1], q2 = qd[2], q3 = qd[3];
  int kb = (h < 2) ? 4*h : 8 + 4*h;
  int b0 = offs[n], b1 = offs[n+1];
  float M = -3.4e38f, D = 0.f, A0 = 0.f, Ax = 0.f, Ay = 0.f, Az = 0.f;
  for (int j = b0; j < b1; ++j) {
    int e = eidx[j];
    const float* me = m + (size_t)e*64;
    float4 kv = *reinterpret_cast<const float4*>(me + kb);
    float l = 0.5f * (kv.x*q0 + kv.y*q1 + kv.z*q2 + kv.w*q3);
    float v0 = me[8+h];
    float vx = me[40+3*h], vy = me[41+3*h], vz = me[42+3*h];
    if (l > M) {
      float sc = __expf(M - l);
      D *= sc; A0 *= sc; Ax *= sc; Ay *= sc; Az *= sc;
      M = l;
    }
    float z = __expf(l - M);
    D += z;
    A0 = fmaf(z, v0, A0);
    Ax = fmaf(z, vx, Ax);
    Ay = fmaf(z, vy, Ay);
    Az = fmaf(z, vz, Az);
  }
  float inv = 1.0f / (D + 1e-9f);
  o0[(size_t)n*8+h] = A0*inv;
  o1[(size_t)n*24+3*h+0] = Ax*inv;
  o1[(size_t)n*24+3*h+1] = Ay*inv;
  o1[(size_t)n*24+3*h+2] = Az*inv;
}

// ---------------- projection + NormSE3 ----------------
__global__ void k_update(const float* __restrict__ o0, const float* __restrict__ o1,
                         const float* __restrict__ f0c, const float* __restrict__ f1c,
                         const float* __restrict__ Wp0, const float* __restrict__ Wp1,
                         const float* __restrict__ ng0v, const float* __restrict__ nb0v,
                         const float* __restrict__ ng1v, const float* __restrict__ nb1v,
                         float* __restrict__ f0o, float* __restrict__ f1o) {
  int t = blockIdx.x * blockDim.x + threadIdx.x;
  int n = t >> 5, o = t & 31;
  if (n >= NN) return;
  float a0 = 0.0f, ax = 0.0f, ay = 0.0f, az = 0.0f;
  for (int c = 0; c < 8; ++c) {
    float w0 = Wp0[c*32+o], w1 = Wp1[c*32+o];
    a0 = fmaf(o0[(size_t)n*8+c], w0, a0);
    ax = fmaf(o1[(size_t)n*24+c*3+0], w1, ax);
    ay = fmaf(o1[(size_t)n*24+c*3+1], w1, ay);
    az = fmaf(o1[(size_t)n*24+c*3+2], w1, az);
  }
  for (int c = 0; c < 32; ++c) {
    float w0 = Wp0[(8+c)*32+o], w1 = Wp1[(8+c)*32+o];
    a0 = fmaf(f0c[(size_t)n*32+c], w0, a0);
    ax = fmaf(f1c[(size_t)n*96+c*3+0], w1, ax);
    ay = fmaf(f1c[(size_t)n*96+c*3+1], w1, ay);
    az = fmaf(f1c[(size_t)n*96+c*3+2], w1, az);
  }
  float nn0 = sqrtf(a0*a0 + 1e-12f);
  float nn1 = sqrtf(ax*ax + ay*ay + az*az + 1e-12f);
  float s0 = nn0, s1 = nn1;
  #pragma unroll
  for (int off = 16; off; off >>= 1) { s0 += __shfl_xor(s0, off, 32); s1 += __shfl_xor(s1, off, 32); }
  float mu0 = s0*(1.0f/32.0f), mu1 = s1*(1.0f/32.0f);
  float d0 = nn0 - mu0, d1 = nn1 - mu1;
  float v0 = d0*d0, v1 = d1*d1;
  #pragma unroll
  for (int off = 16; off; off >>= 1) { v0 += __shfl_xor(v0, off, 32); v1 += __shfl_xor(v1, off, 32); }
  float g0 = fmaxf(d0*rsqrtf(v0*(1.0f/32.0f)+1e-5f)*ng0v[o] + nb0v[o], 0.0f) / nn0;
  float g1 = fmaxf(d1*rsqrtf(v1*(1.0f/32.0f)+1e-5f)*ng1v[o] + nb1v[o], 0.0f) / nn1;
  f0o[(size_t)n*32+o] = a0*g0;
  f1o[(size_t)n*96+o*3+0] = ax*g1;
  f1o[(size_t)n*96+o*3+1] = ay*g1;
  f1o[(size_t)n*96+o*3+2] = az*g1;
}

// ---------------- final conv via MFMA (barrier-free) -> scatter ----------------
__global__ __launch_bounds__(256) void k_fconv_mfma(
    const unsigned short* __restrict__ hbf, const unsigned short* __restrict__ w2s,
    const float* __restrict__ f0, const float* __restrict__ f1,
    const float* __restrict__ rhat, const float* __restrict__ scale,
    const int* __restrict__ src, const int* __restrict__ dst, float* __restrict__ out)
{
  __shared__ float f0s[EB][33];
  __shared__ float t1s[EB][33];
  __shared__ float macc[EB][17];
  __shared__ float scs[EB];
  __shared__ float Rl[4][32][33];
  int tid = threadIdx.x;
  int e0 = blockIdx.x * EB;

  for (int idx = tid; idx < EB; idx += 256) scs[idx] = scale[e0+idx];
  for (int idx = tid; idx < EB*16; idx += 256) macc[idx>>4][idx&15] = 0.0f;
  for (int idx = tid; idx < EB*CC; idx += 256) {
    int e = idx >> 5, c = idx & 31;
    int sn = src[e0+e];
    f0s[e][c] = f0[(size_t)sn*32 + c];
    float a0 = f1[(size_t)sn*96 + c*3 + 0];
    float a1 = f1[(size_t)sn*96 + c*3 + 1];
    float a2 = f1[(size_t)sn*96 + c*3 + 2];
    float rx = rhat[(e0+e)*3+0], ry = rhat[(e0+e)*3+1], rz = rhat[(e0+e)*3+2];
    t1s[e][c] = a0*rx + a1*ry + a2*rz;
  }
  int lane = tid & 63, wv = tid >> 6;
  int cl = lane & 15, rb = (lane >> 4) << 2;
  int le = lane & 31, hh = lane >> 5;
  s16x8 af00, af01, af10, af11;
  {
    const unsigned short* hb = hbf + (size_t)e0*64;
    int row = lane & 15;
    int ko  = (lane >> 4) * 8;
    af00 = *reinterpret_cast<const s16x8*>(hb + (size_t)row*64 + ko);
    af01 = *reinterpret_cast<const s16x8*>(hb + (size_t)row*64 + 32 + ko);
    af10 = *reinterpret_cast<const s16x8*>(hb + (size_t)(row+16)*64 + ko);
    af11 = *reinterpret_cast<const s16x8*>(hb + (size_t)(row+16)*64 + 32 + ko);
  }
  __syncthreads();
  float (*Rw)[33] = Rl[wv];

  for (int i = 0; i < 8; ++i) {
    int g = i*4 + wv;
    const s16x8* bp = reinterpret_cast<const s16x8*>(w2s) + ((size_t)g*4*64 + lane);
    s16x8 b00 = bp[0];
    s16x8 b01 = bp[64];
    s16x8 b10 = bp[128];
    s16x8 b11 = bp[192];
    f32x4 aA0 = {0.f,0.f,0.f,0.f}, aA1 = {0.f,0.f,0.f,0.f};
    f32x4 aB0 = {0.f,0.f,0.f,0.f}, aB1 = {0.f,0.f,0.f,0.f};
    aA0 = __builtin_amdgcn_mfma_f32_16x16x32_bf16(af00, b00, aA0, 0,0,0);
    aA0 = __builtin_amdgcn_mfma_f32_16x16x32_bf16(af01, b01, aA0, 0,0,0);
    aA1 = __builtin_amdgcn_mfma_f32_16x16x32_bf16(af10, b00, aA1, 0,0,0);
    aA1 = __builtin_amdgcn_mfma_f32_16x16x32_bf16(af11, b01, aA1, 0,0,0);
    aB0 = __builtin_amdgcn_mfma_f32_16x16x32_bf16(af00, b10, aB0, 0,0,0);
    aB0 = __builtin_amdgcn_mfma_f32_16x16x32_bf16(af01, b11, aB0, 0,0,0);
    aB1 = __builtin_amdgcn_mfma_f32_16x16x32_bf16(af10, b10, aB1, 0,0,0);
    aB1 = __builtin_amdgcn_mfma_f32_16x16x32_bf16(af11, b11, aB1, 0,0,0);
    #pragma unroll
    for (int r = 0; r < 4; ++r) {
      Rw[cl][rb+r]       = aA0[r];
      Rw[cl][16+rb+r]    = aA1[r];
      Rw[16+cl][rb+r]    = aB0[r];
      Rw[16+cl][16+rb+r] = aB1[r];
    }
    float r16[16];
    #pragma unroll
    for (int j = 0; j < 16; ++j) r16[j] = Rw[hh*16 + j][le];
    const float* mp = (g < 16) ? &f0s[le][hh*16] : &t1s[le][hh*16];
    float p = 0.f;
    #pragma unroll
    for (int j = 0; j < 16; ++j) p = fmaf(r16[j], mp[j], p);
    p += __shfl_xor(p, 32);
    if (hh == 0) macc[le][g & 15] += p;
  }
  __syncthreads();
  for (int idx = tid; idx < EB*16; idx += 256) {
    int e = idx >> 4, o = idx & 15;
    atomicAdd(&out[(size_t)dst[e0+e]*16 + o], macc[e][o]*scs[e]);
  }
}

extern "C" void kernel_launch(void* const* d_in, const int* in_sizes, int n_in,
                              void* d_out, int out_size, void* d_ws, size_t ws_size,
                              hipStream_t stream) {
  (void)in_sizes; (void)n_in; (void)ws_size;
  const float* nf0  = (const float*)d_in[0];
  const float* nf1  = (const float*)d_in[1];
  const float* ef0  = (const float*)d_in[2];
  const float* rel  = (const float*)d_in[3];
  const float* scale= (const float*)d_in[4];
  const int*   src  = (const int*)d_in[5];
  const int*   dst  = (const int*)d_in[6];
  const float* rW1  = (const float*)d_in[7];
  const float* rb1  = (const float*)d_in[8];
  const float* rg   = (const float*)d_in[9];
  const float* rbe  = (const float*)d_in[10];
  const float* rW2  = (const float*)d_in[11];
  const float* Wq0  = (const float*)d_in[12];
  const float* Wq1  = (const float*)d_in[13];
  const float* Wp0  = (const float*)d_in[14];
  const float* Wp1  = (const float*)d_in[15];
  const float* ng0  = (const float*)d_in[16];
  const float* nb0  = (const float*)d_in[17];
  const float* ng1  = (const float*)d_in[18];
  const float* nb1  = (const float*)d_in[19];
  const float* fW1  = (const float*)d_in[20];
  const float* fb1  = (const float*)d_in[21];
  const float* fg   = (const float*)d_in[22];
  const float* fbe  = (const float*)d_in[23];
  const float* fW2  = (const float*)d_in[24];

  float* ws = (float*)d_ws;
  size_t off = 0;
  float* es    = ws + off; off += (size_t)NE*5;
  float* rhat  = ws + off; off += (size_t)NE*3;
  float* m     = ws + off; off += (size_t)NE*64;
  float* q     = ws + off; off += (size_t)NN*32;
  float* o0    = ws + off; off += (size_t)NN*8;
  float* o1    = ws + off; off += (size_t)NN*24;
  float* f0a   = ws + off; off += (size_t)NN*32;
  float* f1a   = ws + off; off += (size_t)NN*96;
  float* f0b   = ws + off; off += (size_t)NN*32;
  float* f1b   = ws + off; off += (size_t)NN*96;
  int* cnt     = (int*)(ws + off); off += NN;
  int* offs    = (int*)(ws + off); off += NN + 1;
  int* cursor  = (int*)(ws + off); off += NN;
  int* eidx    = (int*)(ws + off); off += NE;
  unsigned short* usbase = (unsigned short*)(ws + off);
  unsigned short* hbf  = usbase;                               // NE*64
  unsigned short* w2s0 = hbf  + (size_t)NE*64;                 // 196608
  unsigned short* w2s1 = w2s0 + 196608;
  unsigned short* w2sf = w2s1 + 196608;                        // 65536

  // CSR build over dst (once per launch; dst-only dependent)
  hipMemsetAsync(cnt, 0, NN*sizeof(int), stream);
  k_count<<<NE/256, 256, 0, stream>>>(dst, cnt);
  k_scan<<<1, 1024, 0, stream>>>(cnt, offs, cursor);
  k_fill<<<NE/256, 256, 0, stream>>>(dst, cursor, eidx);

  // weight pre-swizzle (bf16 B-fragment order)
  k_w2cvt<<<96, 256, 0, stream>>>(rW2,            w2s0, 3072);
  k_w2cvt<<<96, 256, 0, stream>>>(rW2 + 64*3072,  w2s1, 3072);
  k_w2cvt<<<32, 256, 0, stream>>>(fW2,            w2sf, 1024);

  k_prep<<<NE/256, 256, 0, stream>>>(rel, ef0, es, rhat);

  const float* f0c = nf0; const float* f1c = nf1;
  float* f0n = f0a; float* f1n = f1a;
  for (int l = 0; l < 2; ++l) {
    k_radial<<<NE*64/256, 256, 0, stream>>>(es, rW1 + l*320, rb1 + l*64, rg + l*64, rbe + l*64, hbf);
    k_conv_mfma<<<NE/EB, 256, 0, stream>>>(hbf, (l == 0) ? w2s0 : w2s1, f0c, f1c, rhat, scale, src, m);
    k_query<<<NN/256, 256, 0, stream>>>(f0c, f1c, Wq0 + l*256, Wq1 + l*256, q);
    k_attn<<<NN*8/256, 256, 0, stream>>>(m, q, offs, eidx, o0, o1);
    k_update<<<NN*32/256, 256, 0, stream>>>(o0, o1, f0c, f1c, Wp0 + l*1280, Wp1 + l*1280,
                                            ng0 + l*32, nb0 + l*32, ng1 + l*32, nb1 + l*32,
                                            f0n, f1n);
    f0c = f0n; f1c = f1n; f0n = f0b; f1n = f1b;
  }
  k_radial<<<NE*64/256, 256, 0, stream>>>(es, fW1, fb1, fg, fbe, hbf);
  hipMemsetAsync(d_out, 0, (size_t)out_size*sizeof(float), stream);
  k_fconv_mfma<<<NE/EB, 256, 0, stream>>>(hbf, w2sf, f0c, f1c, rhat, scale, src, dst, (float*)d_out);
}

// Round 10
// 322.316 us; speedup vs baseline: 3.0153x; 1.0557x over previous
//
#include <hip/hip_runtime.h>
#include <math.h>

#define NN 8192
#define NE 32768
#define CC 32
#define EB 32

typedef __attribute__((ext_vector_type(8))) short s16x8;
typedef __attribute__((ext_vector_type(4))) float f32x4;

__device__ __forceinline__ unsigned short f2bf(float f) {
  unsigned u = __float_as_uint(f);
  u += 0x7FFFu + ((u >> 16) & 1u);
  return (unsigned short)(u >> 16);
}

// ---------------- edge preprocessing ----------------
__global__ void k_prep(const float* __restrict__ rel, const float* __restrict__ ef,
                       float* __restrict__ es, float* __restrict__ rhat) {
  int e = blockIdx.x * blockDim.x + threadIdx.x;
  if (e >= NE) return;
  float x = rel[e*3+0], y = rel[e*3+1], z = rel[e*3+2];
  float rn = sqrtf(x*x + y*y + z*z);
  float inv = 1.0f / (rn + 1e-12f);
  rhat[e*3+0] = x*inv; rhat[e*3+1] = y*inv; rhat[e*3+2] = z*inv;
  es[e*5+0] = rn;
  es[e*5+1] = ef[e*4+0];
  es[e*5+2] = ef[e*4+1];
  es[e*5+3] = ef[e*4+2];
  es[e*5+4] = ef[e*4+3];
}

// ---------------- CSR build over dst ----------------
__global__ void k_count(const int* __restrict__ dst, int* __restrict__ cnt) {
  int e = blockIdx.x * blockDim.x + threadIdx.x;
  if (e < NE) atomicAdd(&cnt[dst[e]], 1);
}

__global__ __launch_bounds__(1024) void k_scan(const int* __restrict__ cnt,
                                               int* __restrict__ offs, int* __restrict__ cursor) {
  __shared__ int part[1024];
  int t = threadIdx.x;
  int base = t * 8;
  int loc[8];
  int s = 0;
  #pragma unroll
  for (int j = 0; j < 8; ++j) { loc[j] = s; s += cnt[base + j]; }
  part[t] = s;
  __syncthreads();
  for (int off = 1; off < 1024; off <<= 1) {
    int v = (t >= off) ? part[t - off] : 0;
    __syncthreads();
    part[t] += v;
    __syncthreads();
  }
  int pre = (t == 0) ? 0 : part[t - 1];
  #pragma unroll
  for (int j = 0; j < 8; ++j) {
    int o = pre + loc[j];
    offs[base + j] = o;
    cursor[base + j] = o;
  }
  if (t == 1023) offs[NN] = part[1023];
}

__global__ void k_fill(const int* __restrict__ dst, int* __restrict__ cursor,
                       int* __restrict__ eidx) {
  int e = blockIdx.x * blockDim.x + threadIdx.x;
  if (e >= NE) return;
  int pos = atomicAdd(&cursor[dst[e]], 1);
  eidx[pos] = e;
}

// ---------------- radial hidden -> bf16 ----------------
__global__ void k_radial(const float* __restrict__ es, const float* __restrict__ W1,
                         const float* __restrict__ b1, const float* __restrict__ g,
                         const float* __restrict__ be, unsigned short* __restrict__ h) {
  int t = blockIdx.x * blockDim.x + threadIdx.x;
  int e = t >> 6, m = t & 63;
  if (e >= NE) return;
  const float* ep = es + (size_t)e*5;
  float v = b1[m];
  v = fmaf(ep[0], W1[0*64+m], v);
  v = fmaf(ep[1], W1[1*64+m], v);
  v = fmaf(ep[2], W1[2*64+m], v);
  v = fmaf(ep[3], W1[3*64+m], v);
  v = fmaf(ep[4], W1[4*64+m], v);
  float s = v;
  #pragma unroll
  for (int off = 32; off; off >>= 1) s += __shfl_xor(s, off);
  float mu = s * (1.0f/64.0f);
  float d = v - mu;
  float s2 = d*d;
  #pragma unroll
  for (int off = 32; off; off >>= 1) s2 += __shfl_xor(s2, off);
  float hv = d * rsqrtf(s2*(1.0f/64.0f) + 1e-5f) * g[m] + be[m];
  h[(size_t)e*64+m] = f2bf(fmaxf(hv, 0.0f));
}

// ---------------- W2 -> bf16, A-fragment order (M = col-in-group) ----------------
// frag f = g*4 + mt*2 + kh ; dst[(f*64+lane)*8+j] = W2[kh*32+(lane>>4)*8+j][g*32+mt*16+(lane&15)]
__global__ void k_w2cvt(const float* __restrict__ W2, unsigned short* __restrict__ dstp, int N) {
  int idx = blockIdx.x * blockDim.x + threadIdx.x;
  int total = (N >> 5) * 4 * 64;   // groups * 4 frags * 64 lanes
  if (idx >= total) return;
  int l = idx & 63;
  int fr = idx >> 6;
  int kh = fr & 1;
  int mt = (fr >> 1) & 1;
  int g  = fr >> 2;
  int kb  = kh*32 + (l >> 4)*8;
  int col = g*32 + mt*16 + (l & 15);
  s16x8 v;
  #pragma unroll
  for (int j = 0; j < 8; ++j) v[j] = (short)f2bf(W2[(size_t)(kb + j)*N + col]);
  *reinterpret_cast<s16x8*>(dstp + (size_t)idx*8) = v;
}

// ---------------- fused conv via transposed MFMA: register epilogue, barrier-free ----------------
// m layout per edge (64 floats): [0..15]=m0, [16 + o*3 + a]=m1[o][a]
// wave: et=wv&1 (edge-tile), gp=wv>>1 (group parity); lane's edge e = et*16+(lane&15) fixed.
__global__ __launch_bounds__(256) void k_conv_mfma(
    const unsigned short* __restrict__ hbf, const unsigned short* __restrict__ w2s,
    const float* __restrict__ f0, const float* __restrict__ f1,
    const float* __restrict__ rhat, const float* __restrict__ scale,
    const int* __restrict__ src, float* __restrict__ m_out)
{
  __shared__ float f0s[EB][33];
  __shared__ float t1s[EB][33];
  __shared__ float f1s[EB][99];
  __shared__ float rhs[EB][4];
  __shared__ float scs[EB];
  __shared__ float macc[EB][81];
  int tid = threadIdx.x;
  int e0 = blockIdx.x * EB;

  for (int idx = tid; idx < EB; idx += 256) {
    rhs[idx][0] = rhat[(e0+idx)*3+0];
    rhs[idx][1] = rhat[(e0+idx)*3+1];
    rhs[idx][2] = rhat[(e0+idx)*3+2];
    scs[idx]    = scale[e0+idx];
  }
  for (int idx = tid; idx < EB*80; idx += 256) macc[idx/80][idx%80] = 0.0f;
  for (int idx = tid; idx < EB*CC; idx += 256) {
    int e = idx >> 5, c = idx & 31;
    int sn = src[e0+e];
    f0s[e][c] = f0[(size_t)sn*32 + c];
    float a0 = f1[(size_t)sn*96 + c*3 + 0];
    float a1 = f1[(size_t)sn*96 + c*3 + 1];
    float a2 = f1[(size_t)sn*96 + c*3 + 2];
    f1s[e][c*3+0] = a0; f1s[e][c*3+1] = a1; f1s[e][c*3+2] = a2;
    float rx = rhat[(e0+e)*3+0], ry = rhat[(e0+e)*3+1], rz = rhat[(e0+e)*3+2];
    t1s[e][c] = a0*rx + a1*ry + a2*rz;
  }
  __syncthreads();

  int lane = tid & 63, wv = tid >> 6;
  int cl = lane & 15;
  int rb = ((lane >> 4) & 3) * 4;     // this lane's col-offset within m-tile
  int ko = (lane >> 4) * 8;           // k-offset for frags
  int et = wv & 1, gp = wv >> 1;
  int e  = et*16 + cl;                // this lane's edge

  // B-frags: h for this edge (fixed all loop)
  const unsigned short* hb = hbf + (size_t)e0*64;
  s16x8 bh0 = *reinterpret_cast<const s16x8*>(hb + (size_t)e*64 + ko);
  s16x8 bh1 = *reinterpret_cast<const s16x8*>(hb + (size_t)e*64 + 32 + ko);

  // F-values for this lane's (edge, 8 cols) — hoisted to registers
  float F0[8], T1[8], F1r[24];
  float rx = rhs[e][0], ry = rhs[e][1], rz = rhs[e][2];
  #pragma unroll
  for (int r = 0; r < 4; ++r) {
    int cA = rb + r, cB = 16 + rb + r;
    F0[r]   = f0s[e][cA];  F0[4+r] = f0s[e][cB];
    T1[r]   = t1s[e][cA];  T1[4+r] = t1s[e][cB];
    #pragma unroll
    for (int a = 0; a < 3; ++a) {
      F1r[r*3+a]    = f1s[e][cA*3+a];
      F1r[12+r*3+a] = f1s[e][cB*3+a];
    }
  }

  const float inv_s3 = 0.57735026919f;
  const float inv_s2 = 0.70710678118f;
  const float c15    = 1.22474487139f;

  for (int i = 0; i < 48; ++i) {
    int g = i*2 + gp;                 // 32-col group, 0..95
    const s16x8* ap = reinterpret_cast<const s16x8*>(w2s) + ((size_t)g*4*64 + lane);
    s16x8 a00 = ap[0];      // mt0 kh0
    s16x8 a01 = ap[64];     // mt0 kh1
    s16x8 a10 = ap[128];    // mt1 kh0
    s16x8 a11 = ap[192];    // mt1 kh1
    f32x4 D0 = {0.f,0.f,0.f,0.f}, D1 = {0.f,0.f,0.f,0.f};
    D0 = __builtin_amdgcn_mfma_f32_16x16x32_bf16(a00, bh0, D0, 0,0,0);
    D0 = __builtin_amdgcn_mfma_f32_16x16x32_bf16(a01, bh1, D0, 0,0,0);
    D1 = __builtin_amdgcn_mfma_f32_16x16x32_bf16(a10, bh0, D1, 0,0,0);
    D1 = __builtin_amdgcn_mfma_f32_16x16x32_bf16(a11, bh1, D1, 0,0,0);
    // D0[r] = R[e][32g + rb+r], D1[r] = R[e][32g + 16+rb+r]
    if (g < 32) {                      // R00 / R01 with f0
      float p = 0.f;
      #pragma unroll
      for (int r = 0; r < 4; ++r) {
        p = fmaf(D0[r], F0[r], p);
        p = fmaf(D1[r], F0[4+r], p);
      }
      p += __shfl_xor(p, 16);
      p += __shfl_xor(p, 32);
      if (lane < 16) macc[e][g] += p;
    } else if (g < 48) {               // R10 with t1
      float p = 0.f;
      #pragma unroll
      for (int r = 0; r < 4; ++r) {
        p = fmaf(D0[r], T1[r], p);
        p = fmaf(D1[r], T1[4+r], p);
      }
      p += __shfl_xor(p, 16);
      p += __shfl_xor(p, 32);
      if (lane < 16) macc[e][g-32] += p;
    } else {                           // R11: V = R*f1, W = R*t1 (j3==2)
      int gg = g - 48, j3 = gg >> 4, o = gg & 15;
      float v0 = 0.f, v1 = 0.f, v2 = 0.f, w = 0.f;
      #pragma unroll
      for (int r = 0; r < 4; ++r) {
        v0 = fmaf(D0[r], F1r[r*3+0], v0);
        v1 = fmaf(D0[r], F1r[r*3+1], v1);
        v2 = fmaf(D0[r], F1r[r*3+2], v2);
        v0 = fmaf(D1[r], F1r[12+r*3+0], v0);
        v1 = fmaf(D1[r], F1r[12+r*3+1], v1);
        v2 = fmaf(D1[r], F1r[12+r*3+2], v2);
      }
      if (j3 == 2) {
        #pragma unroll
        for (int r = 0; r < 4; ++r) {
          w = fmaf(D0[r], T1[r], w);
          w = fmaf(D1[r], T1[4+r], w);
        }
      }
      v0 += __shfl_xor(v0, 16); v0 += __shfl_xor(v0, 32);
      v1 += __shfl_xor(v1, 16); v1 += __shfl_xor(v1, 32);
      v2 += __shfl_xor(v2, 16); v2 += __shfl_xor(v2, 32);
      if (j3 == 2) { w += __shfl_xor(w, 16); w += __shfl_xor(w, 32); }
      if (lane < 16) {
        float u0, u1, u2;
        if (j3 == 0) {
          u0 = v0*inv_s3; u1 = v1*inv_s3; u2 = v2*inv_s3;
        } else if (j3 == 1) {
          u0 = (rz*v1 - ry*v2)*inv_s2;
          u1 = (rx*v2 - rz*v0)*inv_s2;
          u2 = (ry*v0 - rx*v1)*inv_s2;
        } else {
          u0 = c15*(rx*w - v0*(1.0f/3.0f));
          u1 = c15*(ry*w - v1*(1.0f/3.0f));
          u2 = c15*(rz*w - v2*(1.0f/3.0f));
        }
        macc[e][32 + o*3 + 0] += u0;
        macc[e][32 + o*3 + 1] += u1;
        macc[e][32 + o*3 + 2] += u2;
      }
    }
  }
  __syncthreads();
  for (int idx = tid; idx < EB*64; idx += 256) {
    int e2 = idx >> 6, t2 = idx & 63;
    float sc = scs[e2];
    float val;
    if (t2 < 16) {
      val = macc[e2][t2] * sc;
    } else {
      int o = (t2-16)/3, a2 = (t2-16)%3;
      val = (macc[e2][32 + (t2-16)] + macc[e2][16+o]*rhs[e2][a2]) * sc;
    }
    m_out[(size_t)(e0+e2)*64 + t2] = val;
  }
}

// ---------------- queries ----------------
__global__ void k_query(const float* __restrict__ f0, const float* __restrict__ f1,
                        const float* __restrict__ Wq0, const float* __restrict__ Wq1,
                        float* __restrict__ q) {
  int n = blockIdx.x * blockDim.x + threadIdx.x;
  if (n >= NN) return;
  float q0[8]  = {0,0,0,0,0,0,0,0};
  float q1x[8] = {0,0,0,0,0,0,0,0};
  float q1y[8] = {0,0,0,0,0,0,0,0};
  float q1z[8] = {0,0,0,0,0,0,0,0};
  for (int c = 0; c < 32; ++c) {
    float fv = f0[(size_t)n*32+c];
    float fx = f1[(size_t)n*96+c*3+0];
    float fy = f1[(size_t)n*96+c*3+1];
    float fz = f1[(size_t)n*96+c*3+2];
    #pragma unroll
    for (int k = 0; k < 8; ++k) {
      float w0 = Wq0[c*8+k], w1 = Wq1[c*8+k];
      q0[k]  = fmaf(fv, w0, q0[k]);
      q1x[k] = fmaf(fx, w1, q1x[k]);
      q1y[k] = fmaf(fy, w1, q1y[k]);
      q1z[k] = fmaf(fz, w1, q1z[k]);
    }
  }
  #pragma unroll
  for (int k = 0; k < 8; ++k) {
    q[(size_t)n*32+k]         = q0[k];
    q[(size_t)n*32+8+k*3+0]   = q1x[k];
    q[(size_t)n*32+8+k*3+1]   = q1y[k];
    q[(size_t)n*32+8+k*3+2]   = q1z[k];
  }
}

// ---------------- attention: CSR gather + online softmax, thread per (node, head) ----------------
__global__ void k_attn(const float* __restrict__ m, const float* __restrict__ q,
                       const int* __restrict__ offs, const int* __restrict__ eidx,
                       float* __restrict__ o0, float* __restrict__ o1) {
  int idx = blockIdx.x * blockDim.x + threadIdx.x;
  int n = idx >> 3, h = idx & 7;
  if (n >= NN) return;
  const float* qd = q + (size_t)n*32 + 4*h;
  float q0 = qd[0], q1 = qd[1], q2 = qd[2], q3 = qd[3];
  int kb = (h < 2) ? 4*h : 8 + 4*h;
  int b0 = offs[n], b1 = offs[n+1];
  float M = -3.4e38f, D = 0.f, A0 = 0.f, Ax = 0.f, Ay = 0.f, Az = 0.f;
  for (int j = b0; j < b1; ++j) {
    int e = eidx[j];
    const float* me = m + (size_t)e*64;
    float4 kv = *reinterpret_cast<const float4*>(me + kb);
    float l = 0.5f * (kv.x*q0 + kv.y*q1 + kv.z*q2 + kv.w*q3);
    float v0 = me[8+h];
    float vx = me[40+3*h], vy = me[41+3*h], vz = me[42+3*h];
    if (l > M) {
      float sc = __expf(M - l);
      D *= sc; A0 *= sc; Ax *= sc; Ay *= sc; Az *= sc;
      M = l;
    }
    float z = __expf(l - M);
    D += z;
    A0 = fmaf(z, v0, A0);
    Ax = fmaf(z, vx, Ax);
    Ay = fmaf(z, vy, Ay);
    Az = fmaf(z, vz, Az);
  }
  float inv = 1.0f / (D + 1e-9f);
  o0[(size_t)n*8+h] = A0*inv;
  o1[(size_t)n*24+3*h+0] = Ax*inv;
  o1[(size_t)n*24+3*h+1] = Ay*inv;
  o1[(size_t)n*24+3*h+2] = Az*inv;
}

// ---------------- projection + NormSE3 ----------------
__global__ void k_update(const float* __restrict__ o0, const float* __restrict__ o1,
                         const float* __restrict__ f0c, const float* __restrict__ f1c,
                         const float* __restrict__ Wp0, const float* __restrict__ Wp1,
                         const float* __restrict__ ng0v, const float* __restrict__ nb0v,
                         const float* __restrict__ ng1v, const float* __restrict__ nb1v,
                         float* __restrict__ f0o, float* __restrict__ f1o) {
  int t = blockIdx.x * blockDim.x + threadIdx.x;
  int n = t >> 5, o = t & 31;
  if (n >= NN) return;
  float a0 = 0.0f, ax = 0.0f, ay = 0.0f, az = 0.0f;
  for (int c = 0; c < 8; ++c) {
    float w0 = Wp0[c*32+o], w1 = Wp1[c*32+o];
    a0 = fmaf(o0[(size_t)n*8+c], w0, a0);
    ax = fmaf(o1[(size_t)n*24+c*3+0], w1, ax);
    ay = fmaf(o1[(size_t)n*24+c*3+1], w1, ay);
    az = fmaf(o1[(size_t)n*24+c*3+2], w1, az);
  }
  for (int c = 0; c < 32; ++c) {
    float w0 = Wp0[(8+c)*32+o], w1 = Wp1[(8+c)*32+o];
    a0 = fmaf(f0c[(size_t)n*32+c], w0, a0);
    ax = fmaf(f1c[(size_t)n*96+c*3+0], w1, ax);
    ay = fmaf(f1c[(size_t)n*96+c*3+1], w1, ay);
    az = fmaf(f1c[(size_t)n*96+c*3+2], w1, az);
  }
  float nn0 = sqrtf(a0*a0 + 1e-12f);
  float nn1 = sqrtf(ax*ax + ay*ay + az*az + 1e-12f);
  float s0 = nn0, s1 = nn1;
  #pragma unroll
  for (int off = 16; off; off >>= 1) { s0 += __shfl_xor(s0, off, 32); s1 += __shfl_xor(s1, off, 32); }
  float mu0 = s0*(1.0f/32.0f), mu1 = s1*(1.0f/32.0f);
  float d0 = nn0 - mu0, d1 = nn1 - mu1;
  float v0 = d0*d0, v1 = d1*d1;
  #pragma unroll
  for (int off = 16; off; off >>= 1) { v0 += __shfl_xor(v0, off, 32); v1 += __shfl_xor(v1, off, 32); }
  float g0 = fmaxf(d0*rsqrtf(v0*(1.0f/32.0f)+1e-5f)*ng0v[o] + nb0v[o], 0.0f) / nn0;
  float g1 = fmaxf(d1*rsqrtf(v1*(1.0f/32.0f)+1e-5f)*ng1v[o] + nb1v[o], 0.0f) / nn1;
  f0o[(size_t)n*32+o] = a0*g0;
  f1o[(size_t)n*96+o*3+0] = ax*g1;
  f1o[(size_t)n*96+o*3+1] = ay*g1;
  f1o[(size_t)n*96+o*3+2] = az*g1;
}

// ---------------- final conv via transposed MFMA (barrier-free) -> scatter ----------------
__global__ __launch_bounds__(256) void k_fconv_mfma(
    const unsigned short* __restrict__ hbf, const unsigned short* __restrict__ w2s,
    const float* __restrict__ f0, const float* __restrict__ f1,
    const float* __restrict__ rhat, const float* __restrict__ scale,
    const int* __restrict__ src, const int* __restrict__ dst, float* __restrict__ out)
{
  __shared__ float f0s[EB][33];
  __shared__ float t1s[EB][33];
  __shared__ float macc[EB][17];
  __shared__ float scs[EB];
  int tid = threadIdx.x;
  int e0 = blockIdx.x * EB;

  for (int idx = tid; idx < EB; idx += 256) scs[idx] = scale[e0+idx];
  for (int idx = tid; idx < EB*16; idx += 256) macc[idx>>4][idx&15] = 0.0f;
  for (int idx = tid; idx < EB*CC; idx += 256) {
    int e = idx >> 5, c = idx & 31;
    int sn = src[e0+e];
    f0s[e][c] = f0[(size_t)sn*32 + c];
    float a0 = f1[(size_t)sn*96 + c*3 + 0];
    float a1 = f1[(size_t)sn*96 + c*3 + 1];
    float a2 = f1[(size_t)sn*96 + c*3 + 2];
    float rx = rhat[(e0+e)*3+0], ry = rhat[(e0+e)*3+1], rz = rhat[(e0+e)*3+2];
    t1s[e][c] = a0*rx + a1*ry + a2*rz;
  }
  __syncthreads();

  int lane = tid & 63, wv = tid >> 6;
  int cl = lane & 15;
  int rb = ((lane >> 4) & 3) * 4;
  int ko = (lane >> 4) * 8;
  int et = wv & 1, gp = wv >> 1;
  int e  = et*16 + cl;

  const unsigned short* hb = hbf + (size_t)e0*64;
  s16x8 bh0 = *reinterpret_cast<const s16x8*>(hb + (size_t)e*64 + ko);
  s16x8 bh1 = *reinterpret_cast<const s16x8*>(hb + (size_t)e*64 + 32 + ko);

  float F0[8], T1[8];
  #pragma unroll
  for (int r = 0; r < 4; ++r) {
    int cA = rb + r, cB = 16 + rb + r;
    F0[r] = f0s[e][cA];  F0[4+r] = f0s[e][cB];
    T1[r] = t1s[e][cA];  T1[4+r] = t1s[e][cB];
  }

  for (int i = 0; i < 16; ++i) {
    int g = i*2 + gp;                 // 0..31
    const s16x8* ap = reinterpret_cast<const s16x8*>(w2s) + ((size_t)g*4*64 + lane);
    s16x8 a00 = ap[0];
    s16x8 a01 = ap[64];
    s16x8 a10 = ap[128];
    s16x8 a11 = ap[192];
    f32x4 D0 = {0.f,0.f,0.f,0.f}, D1 = {0.f,0.f,0.f,0.f};
    D0 = __builtin_amdgcn_mfma_f32_16x16x32_bf16(a00, bh0, D0, 0,0,0);
    D0 = __builtin_amdgcn_mfma_f32_16x16x32_bf16(a01, bh1, D0, 0,0,0);
    D1 = __builtin_amdgcn_mfma_f32_16x16x32_bf16(a10, bh0, D1, 0,0,0);
    D1 = __builtin_amdgcn_mfma_f32_16x16x32_bf16(a11, bh1, D1, 0,0,0);
    float p = 0.f;
    if (g < 16) {
      #pragma unroll
      for (int r = 0; r < 4; ++r) {
        p = fmaf(D0[r], F0[r], p);
        p = fmaf(D1[r], F0[4+r], p);
      }
    } else {
      #pragma unroll
      for (int r = 0; r < 4; ++r) {
        p = fmaf(D0[r], T1[r], p);
        p = fmaf(D1[r], T1[4+r], p);
      }
    }
    p += __shfl_xor(p, 16);
    p += __shfl_xor(p, 32);
    if (lane < 16) macc[e][g & 15] += p;
  }
  __syncthreads();
  for (int idx = tid; idx < EB*16; idx += 256) {
    int e2 = idx >> 4, o = idx & 15;
    atomicAdd(&out[(size_t)dst[e0+e2]*16 + o], macc[e2][o]*scs[e2]);
  }
}

extern "C" void kernel_launch(void* const* d_in, const int* in_sizes, int n_in,
                              void* d_out, int out_size, void* d_ws, size_t ws_size,
                              hipStream_t stream) {
  (void)in_sizes; (void)n_in; (void)ws_size;
  const float* nf0  = (const float*)d_in[0];
  const float* nf1  = (const float*)d_in[1];
  const float* ef0  = (const float*)d_in[2];
  const float* rel  = (const float*)d_in[3];
  const float* scale= (const float*)d_in[4];
  const int*   src  = (const int*)d_in[5];
  const int*   dst  = (const int*)d_in[6];
  const float* rW1  = (const float*)d_in[7];
  const float* rb1  = (const float*)d_in[8];
  const float* rg   = (const float*)d_in[9];
  const float* rbe  = (const float*)d_in[10];
  const float* rW2  = (const float*)d_in[11];
  const float* Wq0  = (const float*)d_in[12];
  const float* Wq1  = (const float*)d_in[13];
  const float* Wp0  = (const float*)d_in[14];
  const float* Wp1  = (const float*)d_in[15];
  const float* ng0  = (const float*)d_in[16];
  const float* nb0  = (const float*)d_in[17];
  const float* ng1  = (const float*)d_in[18];
  const float* nb1  = (const float*)d_in[19];
  const float* fW1  = (const float*)d_in[20];
  const float* fb1  = (const float*)d_in[21];
  const float* fg   = (const float*)d_in[22];
  const float* fbe  = (const float*)d_in[23];
  const float* fW2  = (const float*)d_in[24];

  float* ws = (float*)d_ws;
  size_t off = 0;
  float* es    = ws + off; off += (size_t)NE*5;
  float* rhat  = ws + off; off += (size_t)NE*3;
  float* m     = ws + off; off += (size_t)NE*64;
  float* q     = ws + off; off += (size_t)NN*32;
  float* o0    = ws + off; off += (size_t)NN*8;
  float* o1    = ws + off; off += (size_t)NN*24;
  float* f0a   = ws + off; off += (size_t)NN*32;
  float* f1a   = ws + off; off += (size_t)NN*96;
  float* f0b   = ws + off; off += (size_t)NN*32;
  float* f1b   = ws + off; off += (size_t)NN*96;
  int* cnt     = (int*)(ws + off); off += NN;
  int* offs    = (int*)(ws + off); off += NN + 1;
  int* cursor  = (int*)(ws + off); off += NN;
  int* eidx    = (int*)(ws + off); off += NE;
  unsigned short* usbase = (unsigned short*)(ws + off);
  unsigned short* hbf  = usbase;                               // NE*64
  unsigned short* w2s0 = hbf  + (size_t)NE*64;                 // 96*4*64*8 = 196608
  unsigned short* w2s1 = w2s0 + 196608;
  unsigned short* w2sf = w2s1 + 196608;                        // 32*4*64*8 = 65536

  // CSR build over dst
  hipMemsetAsync(cnt, 0, NN*sizeof(int), stream);
  k_count<<<NE/256, 256, 0, stream>>>(dst, cnt);
  k_scan<<<1, 1024, 0, stream>>>(cnt, offs, cursor);
  k_fill<<<NE/256, 256, 0, stream>>>(dst, cursor, eidx);

  // weight pre-swizzle (bf16 A-fragment order)
  k_w2cvt<<<96, 256, 0, stream>>>(rW2,            w2s0, 3072);
  k_w2cvt<<<96, 256, 0, stream>>>(rW2 + 64*3072,  w2s1, 3072);
  k_w2cvt<<<32, 256, 0, stream>>>(fW2,            w2sf, 1024);

  k_prep<<<NE/256, 256, 0, stream>>>(rel, ef0, es, rhat);

  const float* f0c = nf0; const float* f1c = nf1;
  float* f0n = f0a; float* f1n = f1a;
  for (int l = 0; l < 2; ++l) {
    k_radial<<<NE*64/256, 256, 0, stream>>>(es, rW1 + l*320, rb1 + l*64, rg + l*64, rbe + l*64, hbf);
    k_conv_mfma<<<NE/EB, 256, 0, stream>>>(hbf, (l == 0) ? w2s0 : w2s1, f0c, f1c, rhat, scale, src, m);
    k_query<<<NN/256, 256, 0, stream>>>(f0c, f1c, Wq0 + l*256, Wq1 + l*256, q);
    k_attn<<<NN*8/256, 256, 0, stream>>>(m, q, offs, eidx, o0, o1);
    k_update<<<NN*32/256, 256, 0, stream>>>(o0, o1, f0c, f1c, Wp0 + l*1280, Wp1 + l*1280,
                                            ng0 + l*32, nb0 + l*32, ng1 + l*32, nb1 + l*32,
                                            f0n, f1n);
    f0c = f0n; f1c = f1n; f0n = f0b; f1n = f1b;
  }
  k_radial<<<NE*64/256, 256, 0, stream>>>(es, fW1, fb1, fg, fbe, hbf);
  hipMemsetAsync(d_out, 0, (size_t)out_size*sizeof(float), stream);
  k_fconv_mfma<<<NE/EB, 256, 0, stream>>>(hbf, w2sf, f0c, f1c, rhat, scale, src, dst, (float*)d_out);
}